// Round 1
// baseline (2103.613 us; speedup 1.0000x reference)
//
#include <hip/hip_runtime.h>
#include <hip/hip_bf16.h>

// Problem constants
#define TOKENS  8192      // B*S = 4*2048
#define HDIM    1024
#define IDIM    2048
#define NEXP    8
#define NPAIRS  16384     // TOKENS * TOP_K

typedef __attribute__((ext_vector_type(8))) short bf16x8;
typedef __attribute__((ext_vector_type(4))) float f32x4;

__device__ __forceinline__ unsigned short f2b(float f){
  unsigned u = __float_as_uint(f);
  u += 0x7fff + ((u >> 16) & 1);   // round-to-nearest-even
  return (unsigned short)(u >> 16);
}

__device__ __forceinline__ void gload16(const void* g, void* l){
  __builtin_amdgcn_global_load_lds(
    (const __attribute__((address_space(1))) unsigned int*)g,
    (__attribute__((address_space(3))) unsigned int*)l, 16, 0, 0);
}

__device__ __forceinline__ float gelu_tanh(float x){
  float x3 = x*x*x;
  float t = tanhf(0.7978845608028654f*(x + 0.044715f*x3));
  return 0.5f*x*(1.0f+t);
}

// ---------------- conversion kernels ----------------

__global__ void conv_hs_k(const float4* __restrict__ src, ushort4* __restrict__ dst, int n4){
  int i = blockIdx.x*blockDim.x + threadIdx.x;
  if (i >= n4) return;
  float4 v = src[i];
  ushort4 o;
  o.x = f2b(v.x); o.y = f2b(v.y); o.z = f2b(v.z); o.w = f2b(v.w);
  dst[i] = o;
}

// src [E][R][C] fp32 -> dst [E][C][R] bf16 (tiled transpose + convert)
__global__ void transpose_conv_k(const float* __restrict__ src, unsigned short* __restrict__ dst,
                                 int R, int C){
  __shared__ float tile[32][33];
  size_t base = (size_t)blockIdx.z * R * C;
  int x = blockIdx.x*32 + threadIdx.x;
  #pragma unroll
  for (int i=0;i<4;++i){
    int y = blockIdx.y*32 + threadIdx.y + i*8;
    tile[threadIdx.y + i*8][threadIdx.x] = src[base + (size_t)y*C + x];
  }
  __syncthreads();
  int xo = blockIdx.y*32 + threadIdx.x;
  #pragma unroll
  for (int i=0;i<4;++i){
    int yo = blockIdx.x*32 + threadIdx.y + i*8;
    dst[base + (size_t)yo*R + xo] = f2b(tile[threadIdx.x][threadIdx.y + i*8]);
  }
}

// ---------------- routing ----------------
// ctl layout (ints): [0..7] cnt, [8..15] cnt2 (assign cursor), [16..23] off

__global__ void router_k(const float* __restrict__ hs, const float* __restrict__ gw,
                         float* __restrict__ lo, int4* __restrict__ tokinfo, int* __restrict__ ctl){
  int wid  = (blockIdx.x*blockDim.x + threadIdx.x) >> 6;   // one wave per token
  int lane = threadIdx.x & 63;
  const float* h = hs + (size_t)wid*HDIM;
  float a0=0,a1=0,a2=0,a3=0,a4=0,a5=0,a6=0,a7=0;
  for (int i = lane; i < HDIM; i += 64){
    float x = h[i];
    const float* g = gw + (size_t)i*NEXP;
    a0 += x*g[0]; a1 += x*g[1]; a2 += x*g[2]; a3 += x*g[3];
    a4 += x*g[4]; a5 += x*g[5]; a6 += x*g[6]; a7 += x*g[7];
  }
  #pragma unroll
  for (int off = 32; off; off >>= 1){
    a0 += __shfl_xor(a0, off); a1 += __shfl_xor(a1, off);
    a2 += __shfl_xor(a2, off); a3 += __shfl_xor(a3, off);
    a4 += __shfl_xor(a4, off); a5 += __shfl_xor(a5, off);
    a6 += __shfl_xor(a6, off); a7 += __shfl_xor(a7, off);
  }
  if (lane == 0){
    float v[8] = {a0,a1,a2,a3,a4,a5,a6,a7};
    float* lp = lo + (size_t)wid*NEXP;
    #pragma unroll
    for (int e=0;e<8;++e) lp[e] = v[e];
    int e0 = 0; float b0 = v[0];
    #pragma unroll
    for (int e=1;e<8;++e){ if (v[e] > b0){ b0 = v[e]; e0 = e; } }
    int e1 = 0; float b1 = -1e30f;
    #pragma unroll
    for (int e=0;e<8;++e){ if (e != e0 && v[e] > b1){ b1 = v[e]; e1 = e; } }
    float ex = expf(b1 - b0);
    float w0 = 1.0f/(1.0f+ex);
    float w1 = ex/(1.0f+ex);
    tokinfo[wid] = make_int4(e0, e1, __float_as_int(w0), __float_as_int(w1));
    atomicAdd(&ctl[e0], 1); atomicAdd(&ctl[e1], 1);
  }
}

__global__ void scan_k(int* ctl){
  if (threadIdx.x == 0){
    int s = 0;
    #pragma unroll
    for (int e=0;e<NEXP;++e){ ctl[16+e] = s; s += ctl[e]; }
  }
}

__global__ void assign_k(const int4* __restrict__ tokinfo, int* ctl,
                         int* __restrict__ ptok, float* __restrict__ pw){
  int t = blockIdx.x*blockDim.x + threadIdx.x;
  if (t >= TOKENS) return;
  int4 ti = tokinfo[t];
  int s0 = ctl[16+ti.x] + atomicAdd(&ctl[8+ti.x], 1);
  ptok[s0] = t; pw[s0] = __int_as_float(ti.z);
  int s1 = ctl[16+ti.y] + atomicAdd(&ctl[8+ti.y], 1);
  ptok[s1] = t; pw[s1] = __int_as_float(ti.w);
}

// ---------------- fused gate+up GEMM (gathered A) ----------------
// C[m,i] = gelu(X_e @ Wg)[m,i] * (X_e @ Wu)[m,i]  -> P (bf16)
// X: [TOKENS][HDIM] bf16; WgT/WuT: [E][IDIM][HDIM] bf16 (transposed weights)

__global__ void moe_gateup_k(const unsigned short* __restrict__ X,
                             const unsigned short* __restrict__ WgT,
                             const unsigned short* __restrict__ WuT,
                             const int* __restrict__ ptok,
                             const int* __restrict__ ctl,
                             unsigned short* __restrict__ P){
  __shared__ unsigned short sA[128*64];
  __shared__ unsigned short sG[128*64];
  __shared__ unsigned short sU[128*64];
  const int e  = blockIdx.z;
  const int mt = blockIdx.y;
  const int nt = blockIdx.x;
  const int cnt = ctl[e];
  if (mt*128 >= cnt) return;
  const int off = ctl[16+e];
  const int t = threadIdx.x;
  const int lane = t & 63, w = t >> 6;
  const int wr = w >> 1, wc = w & 1;

  const int r_in = t >> 3;        // 0..31: row within 32-row staging chunk
  const int cb   = (t & 7) * 8;   // element col within 64-wide K slab

  int tokRow[4];
  #pragma unroll
  for (int c=0;c<4;++c){
    int gm = mt*128 + c*32 + r_in;
    tokRow[c] = ptok[off + (gm < cnt ? gm : 0)];
  }
  const size_t ebase = (size_t)e * IDIM * HDIM;
  int gnRow[4];
  #pragma unroll
  for (int c=0;c<4;++c) gnRow[c] = nt*128 + c*32 + r_in;

  f32x4 accG[4][4] = {};
  f32x4 accU[4][4] = {};

  for (int kt = 0; kt < HDIM/64; ++kt){
    const int k0 = kt*64;
    #pragma unroll
    for (int c=0;c<4;++c)
      gload16(&X[(size_t)tokRow[c]*HDIM + k0 + cb], &sA[c*2048 + t*8]);
    #pragma unroll
    for (int c=0;c<4;++c){
      gload16(&WgT[ebase + (size_t)gnRow[c]*HDIM + k0 + cb], &sG[c*2048 + t*8]);
      gload16(&WuT[ebase + (size_t)gnRow[c]*HDIM + k0 + cb], &sU[c*2048 + t*8]);
    }
    __syncthreads();
    #pragma unroll
    for (int kk=0;kk<2;++kk){
      const int krd = kk*32 + (lane>>4)*8;
      bf16x8 a[4], bg[4], bu[4];
      #pragma unroll
      for (int mi=0;mi<4;++mi)
        a[mi] = *(const bf16x8*)&sA[(wr*64 + mi*16 + (lane&15))*64 + krd];
      #pragma unroll
      for (int ni=0;ni<4;++ni){
        bg[ni] = *(const bf16x8*)&sG[(wc*64 + ni*16 + (lane&15))*64 + krd];
        bu[ni] = *(const bf16x8*)&sU[(wc*64 + ni*16 + (lane&15))*64 + krd];
      }
      #pragma unroll
      for (int mi=0;mi<4;++mi){
        #pragma unroll
        for (int ni=0;ni<4;++ni){
          accG[mi][ni] = __builtin_amdgcn_mfma_f32_16x16x32_bf16(a[mi], bg[ni], accG[mi][ni], 0,0,0);
          accU[mi][ni] = __builtin_amdgcn_mfma_f32_16x16x32_bf16(a[mi], bu[ni], accU[mi][ni], 0,0,0);
        }
      }
    }
    __syncthreads();
  }

  // epilogue: P[off+gm][nt*128+col] = gelu(g)*u   (C/D: col=lane&15, row=(lane>>4)*4+reg)
  const int rsub  = (lane>>4)*4;
  const int csub  = lane & 15;
  #pragma unroll
  for (int mi=0;mi<4;++mi){
    #pragma unroll
    for (int j=0;j<4;++j){
      int gm = mt*128 + wr*64 + mi*16 + rsub + j;
      if (gm >= cnt) continue;
      size_t prow = (size_t)(off+gm)*IDIM + nt*128 + wc*64 + csub;
      #pragma unroll
      for (int ni=0;ni<4;++ni){
        float g = accG[mi][ni][j];
        float u = accU[mi][ni][j];
        P[prow + ni*16] = f2b(gelu_tanh(g)*u);
      }
    }
  }
}

// ---------------- down GEMM (scatter-add epilogue) ----------------
// out[tok] += w * (P_e @ Wd)[m]   ; WdT: [E][HDIM][IDIM] bf16

__global__ void moe_down_k(const unsigned short* __restrict__ P,
                           const unsigned short* __restrict__ WdT,
                           const int* __restrict__ ptok,
                           const float* __restrict__ pw,
                           const int* __restrict__ ctl,
                           float* __restrict__ out){
  __shared__ unsigned short sA[128*64];
  __shared__ unsigned short sB[128*64];
  const int e  = blockIdx.z;
  const int mt = blockIdx.y;
  const int nt = blockIdx.x;
  const int cnt = ctl[e];
  if (mt*128 >= cnt) return;
  const int off = ctl[16+e];
  const int t = threadIdx.x;
  const int lane = t & 63, w = t >> 6;
  const int wr = w >> 1, wc = w & 1;

  const int r_in = t >> 3;
  const int cb   = (t & 7) * 8;

  int aRow[4];
  #pragma unroll
  for (int c=0;c<4;++c){
    int gm = mt*128 + c*32 + r_in;
    aRow[c] = off + (gm < cnt ? gm : cnt-1);
  }
  const size_t ebase = (size_t)e * HDIM * IDIM;
  int gnRow[4];
  #pragma unroll
  for (int c=0;c<4;++c) gnRow[c] = nt*128 + c*32 + r_in;

  f32x4 acc[4][4] = {};

  for (int kt = 0; kt < IDIM/64; ++kt){
    const int k0 = kt*64;
    #pragma unroll
    for (int c=0;c<4;++c)
      gload16(&P[(size_t)aRow[c]*IDIM + k0 + cb], &sA[c*2048 + t*8]);
    #pragma unroll
    for (int c=0;c<4;++c)
      gload16(&WdT[ebase + (size_t)gnRow[c]*IDIM + k0 + cb], &sB[c*2048 + t*8]);
    __syncthreads();
    #pragma unroll
    for (int kk=0;kk<2;++kk){
      const int krd = kk*32 + (lane>>4)*8;
      bf16x8 a[4], b[4];
      #pragma unroll
      for (int mi=0;mi<4;++mi)
        a[mi] = *(const bf16x8*)&sA[(wr*64 + mi*16 + (lane&15))*64 + krd];
      #pragma unroll
      for (int ni=0;ni<4;++ni)
        b[ni] = *(const bf16x8*)&sB[(wc*64 + ni*16 + (lane&15))*64 + krd];
      #pragma unroll
      for (int mi=0;mi<4;++mi){
        #pragma unroll
        for (int ni=0;ni<4;++ni)
          acc[mi][ni] = __builtin_amdgcn_mfma_f32_16x16x32_bf16(a[mi], b[ni], acc[mi][ni], 0,0,0);
      }
    }
    __syncthreads();
  }

  const int rsub = (lane>>4)*4;
  const int csub = lane & 15;
  #pragma unroll
  for (int mi=0;mi<4;++mi){
    #pragma unroll
    for (int j=0;j<4;++j){
      int gm = mt*128 + wr*64 + mi*16 + rsub + j;
      if (gm >= cnt) continue;
      int tok = ptok[off+gm];
      float wt = pw[off+gm];
      size_t orow = (size_t)tok*HDIM + nt*128 + wc*64 + csub;
      #pragma unroll
      for (int ni=0;ni<4;++ni)
        atomicAdd(&out[orow + ni*16], wt*acc[mi][ni][j]);
    }
  }
}

// ---------------- launcher ----------------

extern "C" void kernel_launch(void* const* d_in, const int* in_sizes, int n_in,
                              void* d_out, int out_size, void* d_ws, size_t ws_size,
                              hipStream_t stream){
  const float* hs     = (const float*)d_in[0];
  const float* gw     = (const float*)d_in[1];
  const float* w_gate = (const float*)d_in[2];
  const float* w_up   = (const float*)d_in[3];
  const float* w_down = (const float*)d_in[4];
  float* out_final  = (float*)d_out;
  float* out_logits = out_final + (size_t)TOKENS*HDIM;

  char* wsp = (char*)d_ws;
  int*  ctl      = (int*)wsp;                       // 256 B
  int4* tokinfo  = (int4*)(wsp + 256);              // 128 KiB
  int*  ptok     = (int*)(wsp + 256 + TOKENS*16);
  float* pw      = (float*)(wsp + 256 + TOKENS*16 + NPAIRS*4);
  size_t o = 256 + (size_t)TOKENS*16 + (size_t)NPAIRS*8;
  o = (o + 255) & ~(size_t)255;
  unsigned short* hsb = (unsigned short*)(wsp + o); o += (size_t)TOKENS*HDIM*2;
  unsigned short* wgT = (unsigned short*)(wsp + o); o += (size_t)NEXP*IDIM*HDIM*2;
  unsigned short* wuT = (unsigned short*)(wsp + o); o += (size_t)NEXP*IDIM*HDIM*2;
  unsigned short* wdT = (unsigned short*)(wsp + o); o += (size_t)NEXP*HDIM*IDIM*2;
  unsigned short* P   = (unsigned short*)(wsp + o); o += (size_t)NPAIRS*IDIM*2;
  // total ws usage ≈ 185 MB

  hipMemsetAsync(ctl, 0, 256, stream);
  hipMemsetAsync(out_final, 0, (size_t)TOKENS*HDIM*sizeof(float), stream);

  conv_hs_k<<<(TOKENS*HDIM/4 + 255)/256, 256, 0, stream>>>((const float4*)hs, (ushort4*)hsb, TOKENS*HDIM/4);
  transpose_conv_k<<<dim3(IDIM/32, HDIM/32, NEXP), dim3(32,8), 0, stream>>>(w_gate, wgT, HDIM, IDIM);
  transpose_conv_k<<<dim3(IDIM/32, HDIM/32, NEXP), dim3(32,8), 0, stream>>>(w_up,   wuT, HDIM, IDIM);
  transpose_conv_k<<<dim3(HDIM/32, IDIM/32, NEXP), dim3(32,8), 0, stream>>>(w_down, wdT, IDIM, HDIM);

  router_k<<<TOKENS/4, 256, 0, stream>>>(hs, gw, out_logits, tokinfo, ctl);
  scan_k<<<1, 64, 0, stream>>>(ctl);
  assign_k<<<TOKENS/256, 256, 0, stream>>>(tokinfo, ctl, ptok, pw);

  moe_gateup_k<<<dim3(IDIM/128, 64, NEXP), 256, 0, stream>>>(hsb, wgT, wuT, ptok, ctl, P);
  moe_down_k  <<<dim3(HDIM/128, 64, NEXP), 256, 0, stream>>>(P, wdT, ptok, pw, ctl, out_final);
}

// Round 5
// 895.142 us; speedup vs baseline: 2.3500x; 2.3500x over previous
//
#include <hip/hip_runtime.h>
#include <hip/hip_bf16.h>

// Problem constants
#define TOKENS  8192      // B*S = 4*2048
#define HDIM    1024
#define IDIM    2048
#define NEXP    8
#define NPAIRS  16384     // TOKENS * TOP_K

typedef __attribute__((ext_vector_type(8))) short bf16x8;
typedef __attribute__((ext_vector_type(4))) float f32x4;

__device__ __forceinline__ unsigned short f2b(float f){
  unsigned u = __float_as_uint(f);
  u += 0x7fff + ((u >> 16) & 1);   // round-to-nearest-even
  return (unsigned short)(u >> 16);
}

__device__ __forceinline__ void gload16(const void* g, void* l){
  __builtin_amdgcn_global_load_lds(
    (const __attribute__((address_space(1))) unsigned int*)g,
    (__attribute__((address_space(3))) unsigned int*)l, 16, 0, 0);
}

__device__ __forceinline__ float gelu_tanh(float x){
  float x3 = x*x*x;
  float t = tanhf(0.7978845608028654f*(x + 0.044715f*x3));
  return 0.5f*x*(1.0f+t);
}

// ---------------- conversion kernels ----------------

__global__ void conv_hs_k(const float4* __restrict__ src, ushort4* __restrict__ dst, int n4){
  int i = blockIdx.x*blockDim.x + threadIdx.x;
  if (i >= n4) return;
  float4 v = src[i];
  ushort4 o;
  o.x = f2b(v.x); o.y = f2b(v.y); o.z = f2b(v.z); o.w = f2b(v.w);
  dst[i] = o;
}

// src [E][R][C] fp32 -> dst [E][C][R] bf16 (tiled transpose + convert)
__global__ void transpose_conv_k(const float* __restrict__ src, unsigned short* __restrict__ dst,
                                 int R, int C){
  __shared__ float tile[32][33];
  size_t base = (size_t)blockIdx.z * R * C;
  int x = blockIdx.x*32 + threadIdx.x;
  #pragma unroll
  for (int i=0;i<4;++i){
    int y = blockIdx.y*32 + threadIdx.y + i*8;
    tile[threadIdx.y + i*8][threadIdx.x] = src[base + (size_t)y*C + x];
  }
  __syncthreads();
  int xo = blockIdx.y*32 + threadIdx.x;
  #pragma unroll
  for (int i=0;i<4;++i){
    int yo = blockIdx.x*32 + threadIdx.y + i*8;
    dst[base + (size_t)yo*R + xo] = f2b(tile[threadIdx.x][threadIdx.y + i*8]);
  }
}

// ---------------- routing ----------------
// ctl layout (ints): [0..7] cnt, [8..15] cnt2 (assign cursor), [16..23] off

__global__ void router_k(const float* __restrict__ hs, const float* __restrict__ gw,
                         float* __restrict__ lo, int4* __restrict__ tokinfo, int* __restrict__ ctl){
  int wid  = (blockIdx.x*blockDim.x + threadIdx.x) >> 6;   // one wave per token
  int lane = threadIdx.x & 63;
  const float* h = hs + (size_t)wid*HDIM;
  float a0=0,a1=0,a2=0,a3=0,a4=0,a5=0,a6=0,a7=0;
  for (int i = lane; i < HDIM; i += 64){
    float x = h[i];
    const float* g = gw + (size_t)i*NEXP;
    a0 += x*g[0]; a1 += x*g[1]; a2 += x*g[2]; a3 += x*g[3];
    a4 += x*g[4]; a5 += x*g[5]; a6 += x*g[6]; a7 += x*g[7];
  }
  #pragma unroll
  for (int off = 32; off; off >>= 1){
    a0 += __shfl_xor(a0, off); a1 += __shfl_xor(a1, off);
    a2 += __shfl_xor(a2, off); a3 += __shfl_xor(a3, off);
    a4 += __shfl_xor(a4, off); a5 += __shfl_xor(a5, off);
    a6 += __shfl_xor(a6, off); a7 += __shfl_xor(a7, off);
  }
  if (lane == 0){
    float v[8] = {a0,a1,a2,a3,a4,a5,a6,a7};
    float* lp = lo + (size_t)wid*NEXP;
    #pragma unroll
    for (int e=0;e<8;++e) lp[e] = v[e];
    int e0 = 0; float b0 = v[0];
    #pragma unroll
    for (int e=1;e<8;++e){ if (v[e] > b0){ b0 = v[e]; e0 = e; } }
    int e1 = 0; float b1 = -1e30f;
    #pragma unroll
    for (int e=0;e<8;++e){ if (e != e0 && v[e] > b1){ b1 = v[e]; e1 = e; } }
    float ex = expf(b1 - b0);
    float w0 = 1.0f/(1.0f+ex);
    float w1 = ex/(1.0f+ex);
    tokinfo[wid] = make_int4(e0, e1, __float_as_int(w0), __float_as_int(w1));
    atomicAdd(&ctl[e0], 1); atomicAdd(&ctl[e1], 1);
  }
}

__global__ void scan_k(int* ctl){
  if (threadIdx.x == 0){
    int s = 0;
    #pragma unroll
    for (int e=0;e<NEXP;++e){ ctl[16+e] = s; s += ctl[e]; }
  }
}

__global__ void assign_k(const int4* __restrict__ tokinfo, int* ctl,
                         int* __restrict__ ptok, float* __restrict__ pw){
  int t = blockIdx.x*blockDim.x + threadIdx.x;
  if (t >= TOKENS) return;
  int4 ti = tokinfo[t];
  int s0 = ctl[16+ti.x] + atomicAdd(&ctl[8+ti.x], 1);
  ptok[s0] = t; pw[s0] = __int_as_float(ti.z);
  int s1 = ctl[16+ti.y] + atomicAdd(&ctl[8+ti.y], 1);
  ptok[s1] = t; pw[s1] = __int_as_float(ti.w);
}

// ---------------- fused gate+up GEMM (gathered A) ----------------
// C[m,i] = gelu(X_e @ Wg)[m,i] * (X_e @ Wu)[m,i]  -> P (bf16)
// X: [TOKENS][HDIM] bf16; WgT/WuT: [E][IDIM][HDIM] bf16 (transposed weights)
// grid: (64 mt, 16 nt, 8 e); XCD-chunked swizzle so each XCD keeps 2 weight
// n-slabs (1 MB) L2-resident across all m-tiles.

__global__ __launch_bounds__(256, 2)
void moe_gateup_k(const unsigned short* __restrict__ X,
                  const unsigned short* __restrict__ WgT,
                  const unsigned short* __restrict__ WuT,
                  const int* __restrict__ ptok,
                  const int* __restrict__ ctl,
                  unsigned short* __restrict__ P){
  __shared__ unsigned short sA[128*64];
  __shared__ unsigned short sG[128*64];
  __shared__ unsigned short sU[128*64];
  const int e  = blockIdx.z;
  // bijective XCD-chunk swizzle over the 1024 blocks of this expert
  const int wg = blockIdx.x + 64*blockIdx.y;      // dispatch order within expert
  const int id = (wg & 7)*128 + (wg >> 3);        // XCD c -> ids [c*128, c*128+128)
  const int mt = id & 63;                         // all m-tiles per XCD
  const int nt = id >> 6;                         // 2 n-slabs per XCD
  const int cnt = ctl[e];
  if (mt*128 >= cnt) return;
  const int off = ctl[16+e];
  const int t = threadIdx.x;
  const int lane = t & 63, w = t >> 6;
  const int wr = w >> 1, wc = w & 1;

  const int r_in = t >> 3;        // 0..31: row within 32-row staging chunk
  const int cb   = (t & 7) * 8;   // element col within 64-wide K slab

  int tokRow[4];
  #pragma unroll
  for (int c=0;c<4;++c){
    int gm = mt*128 + c*32 + r_in;
    tokRow[c] = ptok[off + (gm < cnt ? gm : 0)];
  }
  const size_t ebase = (size_t)e * IDIM * HDIM;
  int gnRow[4];
  #pragma unroll
  for (int c=0;c<4;++c) gnRow[c] = nt*128 + c*32 + r_in;

  f32x4 accG[4][4] = {};
  f32x4 accU[4][4] = {};

  for (int kt = 0; kt < HDIM/64; ++kt){
    const int k0 = kt*64;
    #pragma unroll
    for (int c=0;c<4;++c)
      gload16(&X[(size_t)tokRow[c]*HDIM + k0 + cb], &sA[c*2048 + t*8]);
    #pragma unroll
    for (int c=0;c<4;++c){
      gload16(&WgT[ebase + (size_t)gnRow[c]*HDIM + k0 + cb], &sG[c*2048 + t*8]);
      gload16(&WuT[ebase + (size_t)gnRow[c]*HDIM + k0 + cb], &sU[c*2048 + t*8]);
    }
    __syncthreads();
    #pragma unroll
    for (int kk=0;kk<2;++kk){
      const int krd = kk*32 + (lane>>4)*8;
      bf16x8 a[4], bg[4], bu[4];
      #pragma unroll
      for (int mi=0;mi<4;++mi)
        a[mi] = *(const bf16x8*)&sA[(wr*64 + mi*16 + (lane&15))*64 + krd];
      #pragma unroll
      for (int ni=0;ni<4;++ni){
        bg[ni] = *(const bf16x8*)&sG[(wc*64 + ni*16 + (lane&15))*64 + krd];
        bu[ni] = *(const bf16x8*)&sU[(wc*64 + ni*16 + (lane&15))*64 + krd];
      }
      #pragma unroll
      for (int mi=0;mi<4;++mi){
        #pragma unroll
        for (int ni=0;ni<4;++ni){
          accG[mi][ni] = __builtin_amdgcn_mfma_f32_16x16x32_bf16(a[mi], bg[ni], accG[mi][ni], 0,0,0);
          accU[mi][ni] = __builtin_amdgcn_mfma_f32_16x16x32_bf16(a[mi], bu[ni], accU[mi][ni], 0,0,0);
        }
      }
    }
    __syncthreads();
  }

  // epilogue: P[off+gm][nt*128+col] = gelu(g)*u   (C/D: col=lane&15, row=(lane>>4)*4+reg)
  const int rsub  = (lane>>4)*4;
  const int csub  = lane & 15;
  #pragma unroll
  for (int mi=0;mi<4;++mi){
    #pragma unroll
    for (int j=0;j<4;++j){
      int gm = mt*128 + wr*64 + mi*16 + rsub + j;
      if (gm >= cnt) continue;
      size_t prow = (size_t)(off+gm)*IDIM + nt*128 + wc*64 + csub;
      #pragma unroll
      for (int ni=0;ni<4;++ni){
        float g = accG[mi][ni][j];
        float u = accU[mi][ni][j];
        P[prow + ni*16] = f2b(gelu_tanh(g)*u);
      }
    }
  }
}

// ---------------- down GEMM (scatter-add epilogue) ----------------
// out[tok] += w * (P_e @ Wd)[m]   ; WdT: [E][HDIM][IDIM] bf16
// grid: (64 mt, 8 nt, 8 e); XCD swizzle -> 1 weight n-slab per XCD.

__global__ __launch_bounds__(256, 3)
void moe_down_k(const unsigned short* __restrict__ P,
                const unsigned short* __restrict__ WdT,
                const int* __restrict__ ptok,
                const float* __restrict__ pw,
                const int* __restrict__ ctl,
                float* __restrict__ out){
  __shared__ unsigned short sA[128*64];
  __shared__ unsigned short sB[128*64];
  const int e  = blockIdx.z;
  const int wg = blockIdx.x + 64*blockIdx.y;      // 0..511
  const int id = (wg & 7)*64 + (wg >> 3);         // XCD c -> ids [c*64, c*64+64)
  const int mt = id & 63;
  const int nt = id >> 6;
  const int cnt = ctl[e];
  if (mt*128 >= cnt) return;
  const int off = ctl[16+e];
  const int t = threadIdx.x;
  const int lane = t & 63, w = t >> 6;
  const int wr = w >> 1, wc = w & 1;

  const int r_in = t >> 3;
  const int cb   = (t & 7) * 8;

  int aRow[4];
  #pragma unroll
  for (int c=0;c<4;++c){
    int gm = mt*128 + c*32 + r_in;
    aRow[c] = off + (gm < cnt ? gm : cnt-1);
  }
  const size_t ebase = (size_t)e * HDIM * IDIM;
  int gnRow[4];
  #pragma unroll
  for (int c=0;c<4;++c) gnRow[c] = nt*128 + c*32 + r_in;

  f32x4 acc[4][4] = {};

  for (int kt = 0; kt < IDIM/64; ++kt){
    const int k0 = kt*64;
    #pragma unroll
    for (int c=0;c<4;++c)
      gload16(&P[(size_t)aRow[c]*IDIM + k0 + cb], &sA[c*2048 + t*8]);
    #pragma unroll
    for (int c=0;c<4;++c)
      gload16(&WdT[ebase + (size_t)gnRow[c]*IDIM + k0 + cb], &sB[c*2048 + t*8]);
    __syncthreads();
    #pragma unroll
    for (int kk=0;kk<2;++kk){
      const int krd = kk*32 + (lane>>4)*8;
      bf16x8 a[4], b[4];
      #pragma unroll
      for (int mi=0;mi<4;++mi)
        a[mi] = *(const bf16x8*)&sA[(wr*64 + mi*16 + (lane&15))*64 + krd];
      #pragma unroll
      for (int ni=0;ni<4;++ni)
        b[ni] = *(const bf16x8*)&sB[(wc*64 + ni*16 + (lane&15))*64 + krd];
      #pragma unroll
      for (int mi=0;mi<4;++mi){
        #pragma unroll
        for (int ni=0;ni<4;++ni)
          acc[mi][ni] = __builtin_amdgcn_mfma_f32_16x16x32_bf16(a[mi], b[ni], acc[mi][ni], 0,0,0);
      }
    }
    __syncthreads();
  }

  const int rsub = (lane>>4)*4;
  const int csub = lane & 15;
  #pragma unroll
  for (int mi=0;mi<4;++mi){
    #pragma unroll
    for (int j=0;j<4;++j){
      int gm = mt*128 + wr*64 + mi*16 + rsub + j;
      if (gm >= cnt) continue;
      int tok = ptok[off+gm];
      float wt = pw[off+gm];
      size_t orow = (size_t)tok*HDIM + nt*128 + wc*64 + csub;
      #pragma unroll
      for (int ni=0;ni<4;++ni)
        atomicAdd(&out[orow + ni*16], wt*acc[mi][ni][j]);
    }
  }
}

// ---------------- launcher ----------------

extern "C" void kernel_launch(void* const* d_in, const int* in_sizes, int n_in,
                              void* d_out, int out_size, void* d_ws, size_t ws_size,
                              hipStream_t stream){
  const float* hs     = (const float*)d_in[0];
  const float* gw     = (const float*)d_in[1];
  const float* w_gate = (const float*)d_in[2];
  const float* w_up   = (const float*)d_in[3];
  const float* w_down = (const float*)d_in[4];
  float* out_final  = (float*)d_out;
  float* out_logits = out_final + (size_t)TOKENS*HDIM;

  char* wsp = (char*)d_ws;
  int*  ctl      = (int*)wsp;                       // 256 B
  int4* tokinfo  = (int4*)(wsp + 256);              // 128 KiB
  int*  ptok     = (int*)(wsp + 256 + TOKENS*16);
  float* pw      = (float*)(wsp + 256 + TOKENS*16 + NPAIRS*4);
  size_t o = 256 + (size_t)TOKENS*16 + (size_t)NPAIRS*8;
  o = (o + 255) & ~(size_t)255;
  unsigned short* hsb = (unsigned short*)(wsp + o); o += (size_t)TOKENS*HDIM*2;
  unsigned short* wgT = (unsigned short*)(wsp + o); o += (size_t)NEXP*IDIM*HDIM*2;
  unsigned short* wuT = (unsigned short*)(wsp + o); o += (size_t)NEXP*IDIM*HDIM*2;
  unsigned short* wdT = (unsigned short*)(wsp + o); o += (size_t)NEXP*HDIM*IDIM*2;
  unsigned short* P   = (unsigned short*)(wsp + o); o += (size_t)NPAIRS*IDIM*2;
  // total ws usage ≈ 185 MB

  hipMemsetAsync(ctl, 0, 256, stream);
  hipMemsetAsync(out_final, 0, (size_t)TOKENS*HDIM*sizeof(float), stream);

  conv_hs_k<<<(TOKENS*HDIM/4 + 255)/256, 256, 0, stream>>>((const float4*)hs, (ushort4*)hsb, TOKENS*HDIM/4);
  transpose_conv_k<<<dim3(IDIM/32, HDIM/32, NEXP), dim3(32,8), 0, stream>>>(w_gate, wgT, HDIM, IDIM);
  transpose_conv_k<<<dim3(IDIM/32, HDIM/32, NEXP), dim3(32,8), 0, stream>>>(w_up,   wuT, HDIM, IDIM);
  transpose_conv_k<<<dim3(HDIM/32, IDIM/32, NEXP), dim3(32,8), 0, stream>>>(w_down, wdT, IDIM, HDIM);

  router_k<<<TOKENS/4, 256, 0, stream>>>(hs, gw, out_logits, tokinfo, ctl);
  scan_k<<<1, 64, 0, stream>>>(ctl);
  assign_k<<<TOKENS/256, 256, 0, stream>>>(tokinfo, ctl, ptok, pw);

  moe_gateup_k<<<dim3(64, IDIM/128, NEXP), 256, 0, stream>>>(hsb, wgT, wuT, ptok, ctl, P);
  moe_down_k  <<<dim3(64, HDIM/128, NEXP), 256, 0, stream>>>(P, wdT, ptok, pw, ctl, out_final);
}

// Round 6
// 837.545 us; speedup vs baseline: 2.5116x; 1.0688x over previous
//
#include <hip/hip_runtime.h>
#include <hip/hip_bf16.h>

// Problem constants
#define TOKENS  8192      // B*S = 4*2048
#define HDIM    1024
#define IDIM    2048
#define NEXP    8
#define NPAIRS  16384     // TOKENS * TOP_K

typedef __attribute__((ext_vector_type(8))) short bf16x8;
typedef __attribute__((ext_vector_type(4))) float f32x4;

__device__ __forceinline__ unsigned short f2b(float f){
  unsigned u = __float_as_uint(f);
  u += 0x7fff + ((u >> 16) & 1);   // round-to-nearest-even
  return (unsigned short)(u >> 16);
}

__device__ __forceinline__ void gload16(const void* g, void* l){
  __builtin_amdgcn_global_load_lds(
    (const __attribute__((address_space(1))) unsigned int*)g,
    (__attribute__((address_space(3))) unsigned int*)l, 16, 0, 0);
}

__device__ __forceinline__ float gelu_tanh(float x){
  float x3 = x*x*x;
  float t = tanhf(0.7978845608028654f*(x + 0.044715f*x3));
  return 0.5f*x*(1.0f+t);
}

// ---------------- conversion kernels ----------------

__global__ void conv_hs_k(const float4* __restrict__ src, ushort4* __restrict__ dst, int n4){
  int i = blockIdx.x*blockDim.x + threadIdx.x;
  if (i >= n4) return;
  float4 v = src[i];
  ushort4 o;
  o.x = f2b(v.x); o.y = f2b(v.y); o.z = f2b(v.z); o.w = f2b(v.w);
  dst[i] = o;
}

// src [E][R][C] fp32 -> dst [E][C][R] bf16 (tiled transpose + convert)
__global__ void transpose_conv_k(const float* __restrict__ src, unsigned short* __restrict__ dst,
                                 int R, int C){
  __shared__ float tile[32][33];
  size_t base = (size_t)blockIdx.z * R * C;
  int x = blockIdx.x*32 + threadIdx.x;
  #pragma unroll
  for (int i=0;i<4;++i){
    int y = blockIdx.y*32 + threadIdx.y + i*8;
    tile[threadIdx.y + i*8][threadIdx.x] = src[base + (size_t)y*C + x];
  }
  __syncthreads();
  int xo = blockIdx.y*32 + threadIdx.x;
  #pragma unroll
  for (int i=0;i<4;++i){
    int yo = blockIdx.x*32 + threadIdx.y + i*8;
    dst[base + (size_t)yo*R + xo] = f2b(tile[threadIdx.x][threadIdx.y + i*8]);
  }
}

// ---------------- routing ----------------
// ctl layout (ints): [0..7] cnt, [8..15] cnt2 (assign cursor), [16..23] off

__global__ void router_k(const float* __restrict__ hs, const float* __restrict__ gw,
                         float* __restrict__ lo, int4* __restrict__ tokinfo, int* __restrict__ ctl){
  int wid  = (blockIdx.x*blockDim.x + threadIdx.x) >> 6;   // one wave per token
  int lane = threadIdx.x & 63;
  const float* h = hs + (size_t)wid*HDIM;
  float a0=0,a1=0,a2=0,a3=0,a4=0,a5=0,a6=0,a7=0;
  for (int i = lane; i < HDIM; i += 64){
    float x = h[i];
    const float* g = gw + (size_t)i*NEXP;
    a0 += x*g[0]; a1 += x*g[1]; a2 += x*g[2]; a3 += x*g[3];
    a4 += x*g[4]; a5 += x*g[5]; a6 += x*g[6]; a7 += x*g[7];
  }
  #pragma unroll
  for (int off = 32; off; off >>= 1){
    a0 += __shfl_xor(a0, off); a1 += __shfl_xor(a1, off);
    a2 += __shfl_xor(a2, off); a3 += __shfl_xor(a3, off);
    a4 += __shfl_xor(a4, off); a5 += __shfl_xor(a5, off);
    a6 += __shfl_xor(a6, off); a7 += __shfl_xor(a7, off);
  }
  if (lane == 0){
    float v[8] = {a0,a1,a2,a3,a4,a5,a6,a7};
    float* lp = lo + (size_t)wid*NEXP;
    #pragma unroll
    for (int e=0;e<8;++e) lp[e] = v[e];
    int e0 = 0; float b0 = v[0];
    #pragma unroll
    for (int e=1;e<8;++e){ if (v[e] > b0){ b0 = v[e]; e0 = e; } }
    int e1 = 0; float b1 = -1e30f;
    #pragma unroll
    for (int e=0;e<8;++e){ if (e != e0 && v[e] > b1){ b1 = v[e]; e1 = e; } }
    float ex = expf(b1 - b0);
    float w0 = 1.0f/(1.0f+ex);
    float w1 = ex/(1.0f+ex);
    tokinfo[wid] = make_int4(e0, e1, __float_as_int(w0), __float_as_int(w1));
    atomicAdd(&ctl[e0], 1); atomicAdd(&ctl[e1], 1);
  }
}

__global__ void scan_k(int* ctl){
  if (threadIdx.x == 0){
    int s = 0;
    #pragma unroll
    for (int e=0;e<NEXP;++e){ ctl[16+e] = s; s += ctl[e]; }
  }
}

__global__ void assign_k(const int4* __restrict__ tokinfo, int* ctl,
                         int* __restrict__ ptok, float* __restrict__ pw,
                         int2* __restrict__ ppos){
  int t = blockIdx.x*blockDim.x + threadIdx.x;
  if (t >= TOKENS) return;
  int4 ti = tokinfo[t];
  int s0 = ctl[16+ti.x] + atomicAdd(&ctl[8+ti.x], 1);
  ptok[s0] = t; pw[s0] = __int_as_float(ti.z);
  int s1 = ctl[16+ti.y] + atomicAdd(&ctl[8+ti.y], 1);
  ptok[s1] = t; pw[s1] = __int_as_float(ti.w);
  ppos[t] = make_int2(s0, s1);
}

// ---------------- fused gate+up GEMM (gathered A) ----------------
// C[m,i] = gelu(X_e @ Wg)[m,i] * (X_e @ Wu)[m,i]  -> P (bf16)
// X: [TOKENS][HDIM] bf16; WgT/WuT: [E][IDIM][HDIM] bf16 (transposed weights)
// LDS tiles use T2 XOR-swizzle (16B granule ^= row&7) applied BOTH sides:
// inverse-swizzled global source column (LDS dest stays linear for
// global_load_lds, rule #21) + swizzled ds_read granule.

__global__ __launch_bounds__(256, 2)
void moe_gateup_k(const unsigned short* __restrict__ X,
                  const unsigned short* __restrict__ WgT,
                  const unsigned short* __restrict__ WuT,
                  const int* __restrict__ ptok,
                  const int* __restrict__ ctl,
                  unsigned short* __restrict__ P){
  __shared__ unsigned short sA[128*64];
  __shared__ unsigned short sG[128*64];
  __shared__ unsigned short sU[128*64];
  const int e  = blockIdx.z;
  // bijective XCD-chunk swizzle over the 1024 blocks of this expert
  const int wg = blockIdx.x + 64*blockIdx.y;      // dispatch order within expert
  const int id = (wg & 7)*128 + (wg >> 3);        // XCD c -> ids [c*128, c*128+128)
  const int mt = id & 63;                         // all m-tiles per XCD
  const int nt = id >> 6;                         // 2 n-slabs per XCD
  const int cnt = ctl[e];
  if (mt*128 >= cnt) return;
  const int off = ctl[16+e];
  const int t = threadIdx.x;
  const int lane = t & 63, w = t >> 6;
  const int wr = w >> 1, wc = w & 1;

  const int r_in = t >> 3;                         // 0..31: row within 32-row chunk
  const int cb   = (((t & 7) ^ (r_in & 7)) * 8);   // inverse-swizzled src granule

  int tokRow[4];
  #pragma unroll
  for (int c=0;c<4;++c){
    int gm = mt*128 + c*32 + r_in;
    tokRow[c] = ptok[off + (gm < cnt ? gm : 0)];
  }
  const size_t ebase = (size_t)e * IDIM * HDIM;
  int gnRow[4];
  #pragma unroll
  for (int c=0;c<4;++c) gnRow[c] = nt*128 + c*32 + r_in;

  f32x4 accG[4][4] = {};
  f32x4 accU[4][4] = {};

  const int lq = lane >> 4;       // 0..3 quarter-wave
  const int lr = lane & 15;       // fragment row within 16
  const int skey = lane & 7;      // swizzle key = row&7 for all fragment reads

  for (int kt = 0; kt < HDIM/64; ++kt){
    const int k0 = kt*64;
    #pragma unroll
    for (int c=0;c<4;++c)
      gload16(&X[(size_t)tokRow[c]*HDIM + k0 + cb], &sA[c*2048 + t*8]);
    #pragma unroll
    for (int c=0;c<4;++c){
      gload16(&WgT[ebase + (size_t)gnRow[c]*HDIM + k0 + cb], &sG[c*2048 + t*8]);
      gload16(&WuT[ebase + (size_t)gnRow[c]*HDIM + k0 + cb], &sU[c*2048 + t*8]);
    }
    __syncthreads();
    #pragma unroll
    for (int kk=0;kk<2;++kk){
      const int g = ((kk*4 + lq) ^ skey) * 8;   // swizzled granule (elements)
      bf16x8 a[4], bg[4], bu[4];
      #pragma unroll
      for (int mi=0;mi<4;++mi)
        a[mi] = *(const bf16x8*)&sA[(wr*64 + mi*16 + lr)*64 + g];
      #pragma unroll
      for (int ni=0;ni<4;++ni){
        bg[ni] = *(const bf16x8*)&sG[(wc*64 + ni*16 + lr)*64 + g];
        bu[ni] = *(const bf16x8*)&sU[(wc*64 + ni*16 + lr)*64 + g];
      }
      #pragma unroll
      for (int mi=0;mi<4;++mi){
        #pragma unroll
        for (int ni=0;ni<4;++ni){
          accG[mi][ni] = __builtin_amdgcn_mfma_f32_16x16x32_bf16(a[mi], bg[ni], accG[mi][ni], 0,0,0);
          accU[mi][ni] = __builtin_amdgcn_mfma_f32_16x16x32_bf16(a[mi], bu[ni], accU[mi][ni], 0,0,0);
        }
      }
    }
    __syncthreads();
  }

  // epilogue: P[off+gm][nt*128+col] = gelu(g)*u   (C/D: col=lane&15, row=(lane>>4)*4+reg)
  const int rsub  = (lane>>4)*4;
  const int csub  = lane & 15;
  #pragma unroll
  for (int mi=0;mi<4;++mi){
    #pragma unroll
    for (int j=0;j<4;++j){
      int gm = mt*128 + wr*64 + mi*16 + rsub + j;
      if (gm >= cnt) continue;
      size_t prow = (size_t)(off+gm)*IDIM + nt*128 + wc*64 + csub;
      #pragma unroll
      for (int ni=0;ni<4;++ni){
        float g = accG[mi][ni][j];
        float u = accU[mi][ni][j];
        P[prow + ni*16] = f2b(gelu_tanh(g)*u);
      }
    }
  }
}

// ---------------- down GEMM (partial-store epilogue, no atomics) ----------------
// part[pair] = (P_e @ Wd)[m]   ; WdT: [E][HDIM][IDIM] bf16
// grid: (64 mt, 8 nt, 8 e); XCD swizzle -> 1 weight n-slab per XCD.

__global__ __launch_bounds__(256, 3)
void moe_down_k(const unsigned short* __restrict__ P,
                const unsigned short* __restrict__ WdT,
                const int* __restrict__ ctl,
                float* __restrict__ part){
  __shared__ unsigned short sA[128*64];
  __shared__ unsigned short sB[128*64];
  const int e  = blockIdx.z;
  const int wg = blockIdx.x + 64*blockIdx.y;      // 0..511
  const int id = (wg & 7)*64 + (wg >> 3);         // XCD c -> ids [c*64, c*64+64)
  const int mt = id & 63;
  const int nt = id >> 6;
  const int cnt = ctl[e];
  if (mt*128 >= cnt) return;
  const int off = ctl[16+e];
  const int t = threadIdx.x;
  const int lane = t & 63, w = t >> 6;
  const int wr = w >> 1, wc = w & 1;

  const int r_in = t >> 3;
  const int cb   = (((t & 7) ^ (r_in & 7)) * 8);   // inverse-swizzled src granule

  int aRow[4];
  #pragma unroll
  for (int c=0;c<4;++c){
    int gm = mt*128 + c*32 + r_in;
    aRow[c] = off + (gm < cnt ? gm : cnt-1);
  }
  const size_t ebase = (size_t)e * HDIM * IDIM;
  int gnRow[4];
  #pragma unroll
  for (int c=0;c<4;++c) gnRow[c] = nt*128 + c*32 + r_in;

  f32x4 acc[4][4] = {};

  const int lq = lane >> 4;
  const int lr = lane & 15;
  const int skey = lane & 7;

  for (int kt = 0; kt < IDIM/64; ++kt){
    const int k0 = kt*64;
    #pragma unroll
    for (int c=0;c<4;++c)
      gload16(&P[(size_t)aRow[c]*IDIM + k0 + cb], &sA[c*2048 + t*8]);
    #pragma unroll
    for (int c=0;c<4;++c)
      gload16(&WdT[ebase + (size_t)gnRow[c]*IDIM + k0 + cb], &sB[c*2048 + t*8]);
    __syncthreads();
    #pragma unroll
    for (int kk=0;kk<2;++kk){
      const int g = ((kk*4 + lq) ^ skey) * 8;
      bf16x8 a[4], b[4];
      #pragma unroll
      for (int mi=0;mi<4;++mi)
        a[mi] = *(const bf16x8*)&sA[(wr*64 + mi*16 + lr)*64 + g];
      #pragma unroll
      for (int ni=0;ni<4;++ni)
        b[ni] = *(const bf16x8*)&sB[(wc*64 + ni*16 + lr)*64 + g];
      #pragma unroll
      for (int mi=0;mi<4;++mi){
        #pragma unroll
        for (int ni=0;ni<4;++ni)
          acc[mi][ni] = __builtin_amdgcn_mfma_f32_16x16x32_bf16(a[mi], b[ni], acc[mi][ni], 0,0,0);
      }
    }
    __syncthreads();
  }

  const int rsub = (lane>>4)*4;
  const int csub = lane & 15;
  #pragma unroll
  for (int mi=0;mi<4;++mi){
    #pragma unroll
    for (int j=0;j<4;++j){
      int gm = mt*128 + wr*64 + mi*16 + rsub + j;
      if (gm >= cnt) continue;
      size_t orow = (size_t)(off+gm)*HDIM + nt*128 + wc*64 + csub;
      #pragma unroll
      for (int ni=0;ni<4;++ni)
        part[orow + ni*16] = acc[mi][ni][j];
    }
  }
}

// ---------------- combine: out[t] = w0*part[s0] + w1*part[s1] ----------------
// one block per token; 256 threads x float4 = 1024 cols

__global__ void combine_k(const float* __restrict__ part,
                          const int2* __restrict__ ppos,
                          const float* __restrict__ pw,
                          float* __restrict__ out){
  const int tok = blockIdx.x;
  const int c4  = threadIdx.x;
  int2 p = ppos[tok];
  float w0 = pw[p.x], w1 = pw[p.y];
  float4 a = ((const float4*)(part + (size_t)p.x*HDIM))[c4];
  float4 b = ((const float4*)(part + (size_t)p.y*HDIM))[c4];
  float4 o;
  o.x = w0*a.x + w1*b.x;
  o.y = w0*a.y + w1*b.y;
  o.z = w0*a.z + w1*b.z;
  o.w = w0*a.w + w1*b.w;
  ((float4*)(out + (size_t)tok*HDIM))[c4] = o;
}

// ---------------- launcher ----------------

extern "C" void kernel_launch(void* const* d_in, const int* in_sizes, int n_in,
                              void* d_out, int out_size, void* d_ws, size_t ws_size,
                              hipStream_t stream){
  const float* hs     = (const float*)d_in[0];
  const float* gw     = (const float*)d_in[1];
  const float* w_gate = (const float*)d_in[2];
  const float* w_up   = (const float*)d_in[3];
  const float* w_down = (const float*)d_in[4];
  float* out_final  = (float*)d_out;
  float* out_logits = out_final + (size_t)TOKENS*HDIM;

  char* wsp = (char*)d_ws;
  int*  ctl      = (int*)wsp;                       // 256 B
  int4* tokinfo  = (int4*)(wsp + 256);              // 128 KiB
  int*  ptok     = (int*)(wsp + 256 + TOKENS*16);
  float* pw      = (float*)(wsp + 256 + TOKENS*16 + NPAIRS*4);
  size_t o = 256 + (size_t)TOKENS*16 + (size_t)NPAIRS*8;
  o = (o + 255) & ~(size_t)255;
  int2* ppos = (int2*)(wsp + o);                    o += (size_t)TOKENS*8;
  unsigned short* hsb = (unsigned short*)(wsp + o); o += (size_t)TOKENS*HDIM*2;
  unsigned short* wgT = (unsigned short*)(wsp + o); o += (size_t)NEXP*IDIM*HDIM*2;
  unsigned short* wuT = (unsigned short*)(wsp + o); o += (size_t)NEXP*IDIM*HDIM*2;
  unsigned short* wdT = (unsigned short*)(wsp + o); o += (size_t)NEXP*HDIM*IDIM*2;
  unsigned short* P   = (unsigned short*)(wsp + o); o += (size_t)NPAIRS*IDIM*2;
  // part[NPAIRS][HDIM] fp32 (67.1 MB) aliases wgT+wuT (2 x 33.5 MB):
  // down runs after gateup (last reader of wgT/wuT), so reuse is stream-safe.
  float* part = (float*)wgT;

  hipMemsetAsync(ctl, 0, 256, stream);

  conv_hs_k<<<(TOKENS*HDIM/4 + 255)/256, 256, 0, stream>>>((const float4*)hs, (ushort4*)hsb, TOKENS*HDIM/4);
  transpose_conv_k<<<dim3(IDIM/32, HDIM/32, NEXP), dim3(32,8), 0, stream>>>(w_gate, wgT, HDIM, IDIM);
  transpose_conv_k<<<dim3(IDIM/32, HDIM/32, NEXP), dim3(32,8), 0, stream>>>(w_up,   wuT, HDIM, IDIM);
  transpose_conv_k<<<dim3(HDIM/32, IDIM/32, NEXP), dim3(32,8), 0, stream>>>(w_down, wdT, IDIM, HDIM);

  router_k<<<TOKENS/4, 256, 0, stream>>>(hs, gw, out_logits, tokinfo, ctl);
  scan_k<<<1, 64, 0, stream>>>(ctl);
  assign_k<<<TOKENS/256, 256, 0, stream>>>(tokinfo, ctl, ptok, pw, ppos);

  moe_gateup_k<<<dim3(64, IDIM/128, NEXP), 256, 0, stream>>>(hsb, wgT, wuT, ptok, ctl, P);
  moe_down_k  <<<dim3(64, HDIM/128, NEXP), 256, 0, stream>>>(P, wdT, ctl, part);
  combine_k   <<<TOKENS, 256, 0, stream>>>(part, ppos, pw, out_final);
}

// Round 7
// 834.115 us; speedup vs baseline: 2.5220x; 1.0041x over previous
//
#include <hip/hip_runtime.h>
#include <hip/hip_bf16.h>

// Problem constants
#define TOKENS  8192      // B*S = 4*2048
#define HDIM    1024
#define IDIM    2048
#define NEXP    8
#define NPAIRS  16384     // TOKENS * TOP_K

typedef __attribute__((ext_vector_type(8))) short bf16x8;
typedef __attribute__((ext_vector_type(4))) float f32x4;
typedef __attribute__((ext_vector_type(8))) unsigned short u16x8;

__device__ __forceinline__ unsigned short f2b(float f){
  unsigned u = __float_as_uint(f);
  u += 0x7fff + ((u >> 16) & 1);   // round-to-nearest-even
  return (unsigned short)(u >> 16);
}

__device__ __forceinline__ void gload16(const void* g, void* l){
  __builtin_amdgcn_global_load_lds(
    (const __attribute__((address_space(1))) unsigned int*)g,
    (__attribute__((address_space(3))) unsigned int*)l, 16, 0, 0);
}

__device__ __forceinline__ float gelu_tanh(float x){
  float x3 = x*x*x;
  float t = tanhf(0.7978845608028654f*(x + 0.044715f*x3));
  return 0.5f*x*(1.0f+t);
}

// ---------------- conversion kernels ----------------

__global__ void conv_hs_k(const float4* __restrict__ src, ushort4* __restrict__ dst, int n4){
  int i = blockIdx.x*blockDim.x + threadIdx.x;
  if (i >= n4) return;
  float4 v = src[i];
  ushort4 o;
  o.x = f2b(v.x); o.y = f2b(v.y); o.z = f2b(v.z); o.w = f2b(v.w);
  dst[i] = o;
}

// src [E][R][C] fp32 -> dst [E][C][R] bf16; 64x64 tiles, float4 loads + ushort8 stores
__global__ __launch_bounds__(256)
void transpose_conv_k(const float* __restrict__ src, unsigned short* __restrict__ dst,
                      int R, int C){
  __shared__ float tile[64][65];
  size_t base = (size_t)blockIdx.z * R * C;
  const int t = threadIdx.x;
  const int x0 = blockIdx.x*64, y0 = blockIdx.y*64;
  const int rl = t >> 4, c4 = (t & 15) * 4;
  #pragma unroll
  for (int i=0;i<4;++i){
    int r = i*16 + rl;
    float4 v = *(const float4*)&src[base + (size_t)(y0 + r)*C + x0 + c4];
    tile[r][c4+0]=v.x; tile[r][c4+1]=v.y; tile[r][c4+2]=v.z; tile[r][c4+3]=v.w;
  }
  __syncthreads();
  const int c = t >> 2, r0 = (t & 3)*16;
  size_t ob = base + (size_t)(x0 + c)*R + y0;
  #pragma unroll
  for (int v=0; v<2; ++v){
    int r = r0 + v*8;
    u16x8 o;
    #pragma unroll
    for (int j=0;j<8;++j) o[j] = f2b(tile[r+j][c]);
    *(u16x8*)&dst[ob + r] = o;
  }
}

// ---------------- routing ----------------
// ctl layout (ints): [0..7] cnt, [8..15] cnt2 (assign cursor), [16..23] off

__global__ void router_k(const float* __restrict__ hs, const float* __restrict__ gw,
                         float* __restrict__ lo, int4* __restrict__ tokinfo, int* __restrict__ ctl){
  int wid  = (blockIdx.x*blockDim.x + threadIdx.x) >> 6;   // one wave per token
  int lane = threadIdx.x & 63;
  const float* h = hs + (size_t)wid*HDIM;
  float a0=0,a1=0,a2=0,a3=0,a4=0,a5=0,a6=0,a7=0;
  for (int i = lane; i < HDIM; i += 64){
    float x = h[i];
    const float* g = gw + (size_t)i*NEXP;
    a0 += x*g[0]; a1 += x*g[1]; a2 += x*g[2]; a3 += x*g[3];
    a4 += x*g[4]; a5 += x*g[5]; a6 += x*g[6]; a7 += x*g[7];
  }
  #pragma unroll
  for (int off = 32; off; off >>= 1){
    a0 += __shfl_xor(a0, off); a1 += __shfl_xor(a1, off);
    a2 += __shfl_xor(a2, off); a3 += __shfl_xor(a3, off);
    a4 += __shfl_xor(a4, off); a5 += __shfl_xor(a5, off);
    a6 += __shfl_xor(a6, off); a7 += __shfl_xor(a7, off);
  }
  if (lane == 0){
    float v[8] = {a0,a1,a2,a3,a4,a5,a6,a7};
    float* lp = lo + (size_t)wid*NEXP;
    #pragma unroll
    for (int e=0;e<8;++e) lp[e] = v[e];
    int e0 = 0; float b0 = v[0];
    #pragma unroll
    for (int e=1;e<8;++e){ if (v[e] > b0){ b0 = v[e]; e0 = e; } }
    int e1 = 0; float b1 = -1e30f;
    #pragma unroll
    for (int e=0;e<8;++e){ if (e != e0 && v[e] > b1){ b1 = v[e]; e1 = e; } }
    float ex = expf(b1 - b0);
    float w0 = 1.0f/(1.0f+ex);
    float w1 = ex/(1.0f+ex);
    tokinfo[wid] = make_int4(e0, e1, __float_as_int(w0), __float_as_int(w1));
    atomicAdd(&ctl[e0], 1); atomicAdd(&ctl[e1], 1);
  }
}

__global__ void scan_k(int* ctl){
  if (threadIdx.x == 0){
    int s = 0;
    #pragma unroll
    for (int e=0;e<NEXP;++e){ ctl[16+e] = s; s += ctl[e]; }
  }
}

__global__ void assign_k(const int4* __restrict__ tokinfo, int* ctl,
                         int* __restrict__ ptok, float* __restrict__ pw,
                         int2* __restrict__ ppos){
  int t = blockIdx.x*blockDim.x + threadIdx.x;
  if (t >= TOKENS) return;
  int4 ti = tokinfo[t];
  int s0 = ctl[16+ti.x] + atomicAdd(&ctl[8+ti.x], 1);
  ptok[s0] = t; pw[s0] = __int_as_float(ti.z);
  int s1 = ctl[16+ti.y] + atomicAdd(&ctl[8+ti.y], 1);
  ptok[s1] = t; pw[s1] = __int_as_float(ti.w);
  ppos[t] = make_int2(s0, s1);
}

// ---------------- fused gate+up GEMM, 256x128 tile, 512 thr, dbuf pipeline ----
// P[m,i] = gelu(X_e @ Wg)[m,i] * (X_e @ Wu)[m,i]
// LDS per buffer: sA[256][64] (16384) | sG[128][64] (8192) | sU[128][64] (8192)
// T2 swizzle both-sides (rule #21): inverse-swizzled global src granule,
// linear LDS dest, XOR'd ds_read granule. One barrier per K-step; next tile's
// global_load_lds issued BEFORE compute so latency hides under 64 MFMA.

__global__ __launch_bounds__(512, 2)
void moe_gateup_k(const unsigned short* __restrict__ X,
                  const unsigned short* __restrict__ WgT,
                  const unsigned short* __restrict__ WuT,
                  const int* __restrict__ ptok,
                  const int* __restrict__ ctl,
                  unsigned short* __restrict__ P){
  __shared__ unsigned short lds[2*32768];   // 128 KiB
  const int e  = blockIdx.z;
  const int wg = blockIdx.x + 32*blockIdx.y;      // 0..511
  const int id = (wg & 7)*64 + (wg >> 3);         // XCD-chunked, bijective
  const int mt = id & 31;
  const int nt = id >> 5;                         // 0..15
  const int cnt = ctl[e];
  if (mt*256 >= cnt) return;
  const int off = ctl[16+e];
  const int t = threadIdx.x;
  const int lane = t & 63, w = t >> 6;            // 8 waves
  const int wr = w >> 1, wc = w & 1;              // 4 m-strips x 2 n-halves

  const int r_in = t >> 3;                        // 0..63 row within pass
  const int cb   = (((t & 7) ^ (r_in & 7)) * 8);  // inverse-swizzled src granule

  int tokRow[4];
  #pragma unroll
  for (int c=0;c<4;++c){
    int gm = mt*256 + c*64 + r_in;
    tokRow[c] = ptok[off + (gm < cnt ? gm : 0)];
  }
  const size_t ebase = (size_t)e * IDIM * HDIM;
  int gnRow[2];
  #pragma unroll
  for (int c=0;c<2;++c) gnRow[c] = nt*128 + c*64 + r_in;

  f32x4 accG[4][4] = {};
  f32x4 accU[4][4] = {};

  const int lq = lane >> 4, lr = lane & 15, skey = lane & 7;

  auto stage = [&](int bb, int kt){
    const int k0 = kt*64;
    #pragma unroll
    for (int c=0;c<4;++c)
      gload16(&X[(size_t)tokRow[c]*HDIM + k0 + cb], &lds[bb + c*4096 + t*8]);
    #pragma unroll
    for (int c=0;c<2;++c){
      gload16(&WgT[ebase + (size_t)gnRow[c]*HDIM + k0 + cb], &lds[bb + 16384 + c*4096 + t*8]);
      gload16(&WuT[ebase + (size_t)gnRow[c]*HDIM + k0 + cb], &lds[bb + 24576 + c*4096 + t*8]);
    }
  };

  stage(0, 0);
  __syncthreads();
  int cur = 0;
  for (int kt = 0; kt < HDIM/64; ++kt){
    if (kt < HDIM/64 - 1) stage((cur^1)*32768, kt+1);
    const int bb = cur*32768;
    #pragma unroll
    for (int kk=0;kk<2;++kk){
      const int g = ((kk*4 + lq) ^ skey) * 8;
      bf16x8 a[4], bg[4], bu[4];
      #pragma unroll
      for (int mi=0;mi<4;++mi)
        a[mi] = *(const bf16x8*)&lds[bb + (wr*64 + mi*16 + lr)*64 + g];
      #pragma unroll
      for (int ni=0;ni<4;++ni){
        bg[ni] = *(const bf16x8*)&lds[bb + 16384 + (wc*64 + ni*16 + lr)*64 + g];
        bu[ni] = *(const bf16x8*)&lds[bb + 24576 + (wc*64 + ni*16 + lr)*64 + g];
      }
      #pragma unroll
      for (int mi=0;mi<4;++mi){
        #pragma unroll
        for (int ni=0;ni<4;++ni){
          accG[mi][ni] = __builtin_amdgcn_mfma_f32_16x16x32_bf16(a[mi], bg[ni], accG[mi][ni], 0,0,0);
          accU[mi][ni] = __builtin_amdgcn_mfma_f32_16x16x32_bf16(a[mi], bu[ni], accU[mi][ni], 0,0,0);
        }
      }
    }
    __syncthreads();
    cur ^= 1;
  }

  // epilogue (C/D: col=lane&15, row=(lane>>4)*4+reg)
  const int rsub = (lane>>4)*4;
  const int csub = lane & 15;
  #pragma unroll
  for (int mi=0;mi<4;++mi){
    #pragma unroll
    for (int j=0;j<4;++j){
      int gm = mt*256 + wr*64 + mi*16 + rsub + j;
      if (gm >= cnt) continue;
      size_t prow = (size_t)(off+gm)*IDIM + nt*128 + wc*64 + csub;
      #pragma unroll
      for (int ni=0;ni<4;++ni){
        float g = accG[mi][ni][j];
        float u = accU[mi][ni][j];
        P[prow + ni*16] = f2b(gelu_tanh(g)*u);
      }
    }
  }
}

// ---------------- down GEMM, 256x128 tile, 512 thr, dbuf pipeline ----------
// part[pair] = (P_e @ Wd)[m]; LDS/buf: sA[256][64] | sB[128][64] = 48 KiB

__global__ __launch_bounds__(512, 2)
void moe_down_k(const unsigned short* __restrict__ P,
                const unsigned short* __restrict__ WdT,
                const int* __restrict__ ctl,
                float* __restrict__ part){
  __shared__ unsigned short lds[2*24576];   // 96 KiB
  const int e  = blockIdx.z;
  const int wg = blockIdx.x + 32*blockIdx.y;      // 0..255
  const int id = (wg & 7)*32 + (wg >> 3);
  const int mt = id & 31;
  const int nt = id >> 5;                         // 0..7
  const int cnt = ctl[e];
  if (mt*256 >= cnt) return;
  const int off = ctl[16+e];
  const int t = threadIdx.x;
  const int lane = t & 63, w = t >> 6;
  const int wr = w >> 1, wc = w & 1;

  const int r_in = t >> 3;
  const int cb   = (((t & 7) ^ (r_in & 7)) * 8);

  int aRow[4];
  #pragma unroll
  for (int c=0;c<4;++c){
    int gm = mt*256 + c*64 + r_in;
    aRow[c] = off + (gm < cnt ? gm : cnt-1);
  }
  const size_t ebase = (size_t)e * HDIM * IDIM;
  int gnRow[2];
  #pragma unroll
  for (int c=0;c<2;++c) gnRow[c] = nt*128 + c*64 + r_in;

  f32x4 acc[4][4] = {};

  const int lq = lane >> 4, lr = lane & 15, skey = lane & 7;

  auto stage = [&](int bb, int kt){
    const int k0 = kt*64;
    #pragma unroll
    for (int c=0;c<4;++c)
      gload16(&P[(size_t)aRow[c]*IDIM + k0 + cb], &lds[bb + c*4096 + t*8]);
    #pragma unroll
    for (int c=0;c<2;++c)
      gload16(&WdT[ebase + (size_t)gnRow[c]*IDIM + k0 + cb], &lds[bb + 16384 + c*4096 + t*8]);
  };

  stage(0, 0);
  __syncthreads();
  int cur = 0;
  for (int kt = 0; kt < IDIM/64; ++kt){
    if (kt < IDIM/64 - 1) stage((cur^1)*24576, kt+1);
    const int bb = cur*24576;
    #pragma unroll
    for (int kk=0;kk<2;++kk){
      const int g = ((kk*4 + lq) ^ skey) * 8;
      bf16x8 a[4], b[4];
      #pragma unroll
      for (int mi=0;mi<4;++mi)
        a[mi] = *(const bf16x8*)&lds[bb + (wr*64 + mi*16 + lr)*64 + g];
      #pragma unroll
      for (int ni=0;ni<4;++ni)
        b[ni] = *(const bf16x8*)&lds[bb + 16384 + (wc*64 + ni*16 + lr)*64 + g];
      #pragma unroll
      for (int mi=0;mi<4;++mi){
        #pragma unroll
        for (int ni=0;ni<4;++ni)
          acc[mi][ni] = __builtin_amdgcn_mfma_f32_16x16x32_bf16(a[mi], b[ni], acc[mi][ni], 0,0,0);
      }
    }
    __syncthreads();
    cur ^= 1;
  }

  const int rsub = (lane>>4)*4;
  const int csub = lane & 15;
  #pragma unroll
  for (int mi=0;mi<4;++mi){
    #pragma unroll
    for (int j=0;j<4;++j){
      int gm = mt*256 + wr*64 + mi*16 + rsub + j;
      if (gm >= cnt) continue;
      size_t orow = (size_t)(off+gm)*HDIM + nt*128 + wc*64 + csub;
      #pragma unroll
      for (int ni=0;ni<4;++ni)
        part[orow + ni*16] = acc[mi][ni][j];
    }
  }
}

// ---------------- combine: out[t] = w0*part[s0] + w1*part[s1] ----------------

__global__ void combine_k(const float* __restrict__ part,
                          const int2* __restrict__ ppos,
                          const float* __restrict__ pw,
                          float* __restrict__ out){
  const int tok = blockIdx.x;
  const int c4  = threadIdx.x;
  int2 p = ppos[tok];
  float w0 = pw[p.x], w1 = pw[p.y];
  float4 a = ((const float4*)(part + (size_t)p.x*HDIM))[c4];
  float4 b = ((const float4*)(part + (size_t)p.y*HDIM))[c4];
  float4 o;
  o.x = w0*a.x + w1*b.x;
  o.y = w0*a.y + w1*b.y;
  o.z = w0*a.z + w1*b.z;
  o.w = w0*a.w + w1*b.w;
  ((float4*)(out + (size_t)tok*HDIM))[c4] = o;
}

// ---------------- launcher ----------------

extern "C" void kernel_launch(void* const* d_in, const int* in_sizes, int n_in,
                              void* d_out, int out_size, void* d_ws, size_t ws_size,
                              hipStream_t stream){
  const float* hs     = (const float*)d_in[0];
  const float* gw     = (const float*)d_in[1];
  const float* w_gate = (const float*)d_in[2];
  const float* w_up   = (const float*)d_in[3];
  const float* w_down = (const float*)d_in[4];
  float* out_final  = (float*)d_out;
  float* out_logits = out_final + (size_t)TOKENS*HDIM;

  char* wsp = (char*)d_ws;
  int*  ctl      = (int*)wsp;                       // 256 B
  int4* tokinfo  = (int4*)(wsp + 256);              // 128 KiB
  int*  ptok     = (int*)(wsp + 256 + TOKENS*16);
  float* pw      = (float*)(wsp + 256 + TOKENS*16 + NPAIRS*4);
  size_t o = 256 + (size_t)TOKENS*16 + (size_t)NPAIRS*8;
  o = (o + 255) & ~(size_t)255;
  int2* ppos = (int2*)(wsp + o);                    o += (size_t)TOKENS*8;
  unsigned short* hsb = (unsigned short*)(wsp + o); o += (size_t)TOKENS*HDIM*2;
  unsigned short* wgT = (unsigned short*)(wsp + o); o += (size_t)NEXP*IDIM*HDIM*2;
  unsigned short* wuT = (unsigned short*)(wsp + o); o += (size_t)NEXP*IDIM*HDIM*2;
  unsigned short* wdT = (unsigned short*)(wsp + o); o += (size_t)NEXP*HDIM*IDIM*2;
  unsigned short* P   = (unsigned short*)(wsp + o); o += (size_t)NPAIRS*IDIM*2;
  // part[NPAIRS][HDIM] fp32 (67.1 MB) aliases wgT+wuT (down runs after gateup)
  float* part = (float*)wgT;

  hipMemsetAsync(ctl, 0, 256, stream);

  conv_hs_k<<<(TOKENS*HDIM/4 + 255)/256, 256, 0, stream>>>((const float4*)hs, (ushort4*)hsb, TOKENS*HDIM/4);
  transpose_conv_k<<<dim3(IDIM/64, HDIM/64, NEXP), 256, 0, stream>>>(w_gate, wgT, HDIM, IDIM);
  transpose_conv_k<<<dim3(IDIM/64, HDIM/64, NEXP), 256, 0, stream>>>(w_up,   wuT, HDIM, IDIM);
  transpose_conv_k<<<dim3(HDIM/64, IDIM/64, NEXP), 256, 0, stream>>>(w_down, wdT, IDIM, HDIM);

  router_k<<<TOKENS/4, 256, 0, stream>>>(hs, gw, out_logits, tokinfo, ctl);
  scan_k<<<1, 64, 0, stream>>>(ctl);
  assign_k<<<TOKENS/256, 256, 0, stream>>>(tokinfo, ctl, ptok, pw, ppos);

  moe_gateup_k<<<dim3(32, 16, NEXP), 512, 0, stream>>>(hsb, wgT, wuT, ptok, ctl, P);
  moe_down_k  <<<dim3(32, 8, NEXP), 512, 0, stream>>>(P, wdT, ctl, part);
  combine_k   <<<TOKENS, 256, 0, stream>>>(part, ppos, pw, out_final);
}

// Round 8
// 571.713 us; speedup vs baseline: 3.6795x; 1.4590x over previous
//
#include <hip/hip_runtime.h>
#include <hip/hip_bf16.h>

// Problem constants
#define TOKENS  8192      // B*S = 4*2048
#define HDIM    1024
#define IDIM    2048
#define NEXP    8
#define NPAIRS  16384     // TOKENS * TOP_K

typedef __attribute__((ext_vector_type(8))) short bf16x8;
typedef __attribute__((ext_vector_type(4))) float f32x4;
typedef __attribute__((ext_vector_type(8))) unsigned short u16x8;

__device__ __forceinline__ unsigned short f2b(float f){
  unsigned u = __float_as_uint(f);
  u += 0x7fff + ((u >> 16) & 1);   // round-to-nearest-even
  return (unsigned short)(u >> 16);
}

__device__ __forceinline__ void gload16(const void* g, void* l){
  __builtin_amdgcn_global_load_lds(
    (const __attribute__((address_space(1))) unsigned int*)g,
    (__attribute__((address_space(3))) unsigned int*)l, 16, 0, 0);
}

__device__ __forceinline__ float gelu_tanh(float x){
  float x3 = x*x*x;
  float t = tanhf(0.7978845608028654f*(x + 0.044715f*x3));
  return 0.5f*x*(1.0f+t);
}

// ---------------- conversion kernels ----------------

__global__ void conv_hs_k(const float4* __restrict__ src, ushort4* __restrict__ dst, int n4){
  int i = blockIdx.x*blockDim.x + threadIdx.x;
  if (i >= n4) return;
  float4 v = src[i];
  ushort4 o;
  o.x = f2b(v.x); o.y = f2b(v.y); o.z = f2b(v.z); o.w = f2b(v.w);
  dst[i] = o;
}

// src [E][R][C] fp32 -> dst [E][C][R] bf16; 64x64 tiles, float4 loads + ushort8 stores
__global__ __launch_bounds__(256)
void transpose_conv_k(const float* __restrict__ src, unsigned short* __restrict__ dst,
                      int R, int C){
  __shared__ float tile[64][65];
  size_t base = (size_t)blockIdx.z * R * C;
  const int t = threadIdx.x;
  const int x0 = blockIdx.x*64, y0 = blockIdx.y*64;
  const int rl = t >> 4, c4 = (t & 15) * 4;
  #pragma unroll
  for (int i=0;i<4;++i){
    int r = i*16 + rl;
    float4 v = *(const float4*)&src[base + (size_t)(y0 + r)*C + x0 + c4];
    tile[r][c4+0]=v.x; tile[r][c4+1]=v.y; tile[r][c4+2]=v.z; tile[r][c4+3]=v.w;
  }
  __syncthreads();
  const int c = t >> 2, r0 = (t & 3)*16;
  size_t ob = base + (size_t)(x0 + c)*R + y0;
  #pragma unroll
  for (int v=0; v<2; ++v){
    int r = r0 + v*8;
    u16x8 o;
    #pragma unroll
    for (int j=0;j<8;++j) o[j] = f2b(tile[r+j][c]);
    *(u16x8*)&dst[ob + r] = o;
  }
}

// ---------------- routing ----------------
// ctl layout (ints): [0..7] cnt, [8..15] reserve cursor, [16..23] off

// router: logits + top2 + weights. NO atomics (16384 same-line device atomics
// serialized ~200us in r6/r7).
__global__ void router_k(const float* __restrict__ hs, const float* __restrict__ gw,
                         float* __restrict__ lo, int4* __restrict__ tokinfo){
  int wid  = (blockIdx.x*blockDim.x + threadIdx.x) >> 6;   // one wave per token
  int lane = threadIdx.x & 63;
  const float* h = hs + (size_t)wid*HDIM;
  float a0=0,a1=0,a2=0,a3=0,a4=0,a5=0,a6=0,a7=0;
  for (int i = lane; i < HDIM; i += 64){
    float x = h[i];
    const float4 g0 = *(const float4*)(gw + (size_t)i*NEXP);
    const float4 g1 = *(const float4*)(gw + (size_t)i*NEXP + 4);
    a0 += x*g0.x; a1 += x*g0.y; a2 += x*g0.z; a3 += x*g0.w;
    a4 += x*g1.x; a5 += x*g1.y; a6 += x*g1.z; a7 += x*g1.w;
  }
  #pragma unroll
  for (int off = 32; off; off >>= 1){
    a0 += __shfl_xor(a0, off); a1 += __shfl_xor(a1, off);
    a2 += __shfl_xor(a2, off); a3 += __shfl_xor(a3, off);
    a4 += __shfl_xor(a4, off); a5 += __shfl_xor(a5, off);
    a6 += __shfl_xor(a6, off); a7 += __shfl_xor(a7, off);
  }
  if (lane == 0){
    float v[8] = {a0,a1,a2,a3,a4,a5,a6,a7};
    float* lp = lo + (size_t)wid*NEXP;
    #pragma unroll
    for (int e=0;e<8;++e) lp[e] = v[e];
    int e0 = 0; float b0 = v[0];
    #pragma unroll
    for (int e=1;e<8;++e){ if (v[e] > b0){ b0 = v[e]; e0 = e; } }
    int e1 = 0; float b1 = -1e30f;
    #pragma unroll
    for (int e=0;e<8;++e){ if (e != e0 && v[e] > b1){ b1 = v[e]; e1 = e; } }
    float ex = expf(b1 - b0);
    float w0 = 1.0f/(1.0f+ex);
    float w1 = ex/(1.0f+ex);
    tokinfo[wid] = make_int4(e0, e1, __float_as_int(w0), __float_as_int(w1));
  }
}

// per-block LDS histogram -> 8 global atomics per block (32 blocks = 256 total)
__global__ __launch_bounds__(256)
void hist_k(const int4* __restrict__ tokinfo, int* __restrict__ ctl){
  __shared__ int h[8];
  if (threadIdx.x < 8) h[threadIdx.x] = 0;
  __syncthreads();
  int4 ti = tokinfo[blockIdx.x*256 + threadIdx.x];
  atomicAdd(&h[ti.x], 1); atomicAdd(&h[ti.y], 1);
  __syncthreads();
  if (threadIdx.x < 8) atomicAdd(&ctl[threadIdx.x], h[threadIdx.x]);
}

__global__ void scan_k(int* ctl){
  if (threadIdx.x == 0){
    int s = 0;
    #pragma unroll
    for (int e=0;e<NEXP;++e){ ctl[16+e] = s; s += ctl[e]; }
  }
}

// atomic-light assign: within-block ranks via ballot/popc + LDS wave prefix;
// one atomicAdd per (block,expert) reserves the block's range.
__global__ __launch_bounds__(256)
void assign_k(const int4* __restrict__ tokinfo, int* ctl,
              int* __restrict__ ptok, float* __restrict__ pw,
              int2* __restrict__ ppos){
  __shared__ int wcnt0[4][8], wcnt1[4][8];
  __shared__ int woff0[4][8], woff1[4][8];
  __shared__ int btot0[8], blkbase[8];
  const int tid = threadIdx.x, lane = tid & 63, wv = tid >> 6;
  const int tok = blockIdx.x*256 + tid;
  int4 ti = tokinfo[tok];
  const unsigned long long below = (1ull << lane) - 1ull;
  int r0 = 0, r1 = 0;
  #pragma unroll
  for (int e=0;e<8;++e){
    unsigned long long b0 = __ballot(ti.x == e);
    unsigned long long b1 = __ballot(ti.y == e);
    if (ti.x == e) r0 = __popcll(b0 & below);
    if (ti.y == e) r1 = __popcll(b1 & below);
    if (lane == 0){ wcnt0[wv][e] = __popcll(b0); wcnt1[wv][e] = __popcll(b1); }
  }
  __syncthreads();
  if (tid < 8){
    const int e = tid;
    int s0 = 0, s1 = 0;
    #pragma unroll
    for (int w=0;w<4;++w){ woff0[w][e] = s0; s0 += wcnt0[w][e]; }
    btot0[e] = s0;
    #pragma unroll
    for (int w=0;w<4;++w){ woff1[w][e] = s1; s1 += wcnt1[w][e]; }
    blkbase[e] = atomicAdd(&ctl[8+e], s0 + s1);
  }
  __syncthreads();
  const int e0 = ti.x, e1 = ti.y;
  int p0 = ctl[16+e0] + blkbase[e0] + woff0[wv][e0] + r0;
  int p1 = ctl[16+e1] + blkbase[e1] + btot0[e1] + woff1[wv][e1] + r1;
  ptok[p0] = tok; pw[p0] = __int_as_float(ti.z);
  ptok[p1] = tok; pw[p1] = __int_as_float(ti.w);
  ppos[tok] = make_int2(p0, p1);
}

// ---------------- fused gate+up GEMM, 256x128 tile, 512 thr, dbuf pipeline ----
// P[m,i] = gelu(X_e @ Wg)[m,i] * (X_e @ Wu)[m,i]
// T2 swizzle both-sides (rule #21); one barrier per K-step, stage-early.

__global__ __launch_bounds__(512, 2)
void moe_gateup_k(const unsigned short* __restrict__ X,
                  const unsigned short* __restrict__ WgT,
                  const unsigned short* __restrict__ WuT,
                  const int* __restrict__ ptok,
                  const int* __restrict__ ctl,
                  unsigned short* __restrict__ P){
  __shared__ unsigned short lds[2*32768];   // 128 KiB
  const int e  = blockIdx.z;
  const int wg = blockIdx.x + 32*blockIdx.y;      // 0..511
  const int id = (wg & 7)*64 + (wg >> 3);         // XCD-chunked, bijective
  const int mt = id & 31;
  const int nt = id >> 5;                         // 0..15
  const int cnt = ctl[e];
  if (mt*256 >= cnt) return;
  const int off = ctl[16+e];
  const int t = threadIdx.x;
  const int lane = t & 63, w = t >> 6;            // 8 waves
  const int wr = w >> 1, wc = w & 1;              // 4 m-strips x 2 n-halves

  const int r_in = t >> 3;                        // 0..63 row within pass
  const int cb   = (((t & 7) ^ (r_in & 7)) * 8);  // inverse-swizzled src granule

  int tokRow[4];
  #pragma unroll
  for (int c=0;c<4;++c){
    int gm = mt*256 + c*64 + r_in;
    tokRow[c] = ptok[off + (gm < cnt ? gm : 0)];
  }
  const size_t ebase = (size_t)e * IDIM * HDIM;
  int gnRow[2];
  #pragma unroll
  for (int c=0;c<2;++c) gnRow[c] = nt*128 + c*64 + r_in;

  f32x4 accG[4][4] = {};
  f32x4 accU[4][4] = {};

  const int lq = lane >> 4, lr = lane & 15, skey = lane & 7;

  auto stage = [&](int bb, int kt){
    const int k0 = kt*64;
    #pragma unroll
    for (int c=0;c<4;++c)
      gload16(&X[(size_t)tokRow[c]*HDIM + k0 + cb], &lds[bb + c*4096 + t*8]);
    #pragma unroll
    for (int c=0;c<2;++c){
      gload16(&WgT[ebase + (size_t)gnRow[c]*HDIM + k0 + cb], &lds[bb + 16384 + c*4096 + t*8]);
      gload16(&WuT[ebase + (size_t)gnRow[c]*HDIM + k0 + cb], &lds[bb + 24576 + c*4096 + t*8]);
    }
  };

  stage(0, 0);
  __syncthreads();
  int cur = 0;
  for (int kt = 0; kt < HDIM/64; ++kt){
    if (kt < HDIM/64 - 1) stage((cur^1)*32768, kt+1);
    const int bb = cur*32768;
    #pragma unroll
    for (int kk=0;kk<2;++kk){
      const int g = ((kk*4 + lq) ^ skey) * 8;
      bf16x8 a[4], bg[4], bu[4];
      #pragma unroll
      for (int mi=0;mi<4;++mi)
        a[mi] = *(const bf16x8*)&lds[bb + (wr*64 + mi*16 + lr)*64 + g];
      #pragma unroll
      for (int ni=0;ni<4;++ni){
        bg[ni] = *(const bf16x8*)&lds[bb + 16384 + (wc*64 + ni*16 + lr)*64 + g];
        bu[ni] = *(const bf16x8*)&lds[bb + 24576 + (wc*64 + ni*16 + lr)*64 + g];
      }
      #pragma unroll
      for (int mi=0;mi<4;++mi){
        #pragma unroll
        for (int ni=0;ni<4;++ni){
          accG[mi][ni] = __builtin_amdgcn_mfma_f32_16x16x32_bf16(a[mi], bg[ni], accG[mi][ni], 0,0,0);
          accU[mi][ni] = __builtin_amdgcn_mfma_f32_16x16x32_bf16(a[mi], bu[ni], accU[mi][ni], 0,0,0);
        }
      }
    }
    __syncthreads();
    cur ^= 1;
  }

  // epilogue (C/D: col=lane&15, row=(lane>>4)*4+reg)
  const int rsub = (lane>>4)*4;
  const int csub = lane & 15;
  #pragma unroll
  for (int mi=0;mi<4;++mi){
    #pragma unroll
    for (int j=0;j<4;++j){
      int gm = mt*256 + wr*64 + mi*16 + rsub + j;
      if (gm >= cnt) continue;
      size_t prow = (size_t)(off+gm)*IDIM + nt*128 + wc*64 + csub;
      #pragma unroll
      for (int ni=0;ni<4;++ni){
        float g = accG[mi][ni][j];
        float u = accU[mi][ni][j];
        P[prow + ni*16] = f2b(gelu_tanh(g)*u);
      }
    }
  }
}

// ---------------- down GEMM, 256x128 tile, 512 thr, dbuf pipeline ----------
// part[pair] = (P_e @ Wd)[m]; LDS/buf: sA[256][64] | sB[128][64] = 48 KiB

__global__ __launch_bounds__(512, 2)
void moe_down_k(const unsigned short* __restrict__ P,
                const unsigned short* __restrict__ WdT,
                const int* __restrict__ ctl,
                float* __restrict__ part){
  __shared__ unsigned short lds[2*24576];   // 96 KiB
  const int e  = blockIdx.z;
  const int wg = blockIdx.x + 32*blockIdx.y;      // 0..255
  const int id = (wg & 7)*32 + (wg >> 3);
  const int mt = id & 31;
  const int nt = id >> 5;                         // 0..7
  const int cnt = ctl[e];
  if (mt*256 >= cnt) return;
  const int off = ctl[16+e];
  const int t = threadIdx.x;
  const int lane = t & 63, w = t >> 6;
  const int wr = w >> 1, wc = w & 1;

  const int r_in = t >> 3;
  const int cb   = (((t & 7) ^ (r_in & 7)) * 8);

  int aRow[4];
  #pragma unroll
  for (int c=0;c<4;++c){
    int gm = mt*256 + c*64 + r_in;
    aRow[c] = off + (gm < cnt ? gm : cnt-1);
  }
  const size_t ebase = (size_t)e * HDIM * IDIM;
  int gnRow[2];
  #pragma unroll
  for (int c=0;c<2;++c) gnRow[c] = nt*128 + c*64 + r_in;

  f32x4 acc[4][4] = {};

  const int lq = lane >> 4, lr = lane & 15, skey = lane & 7;

  auto stage = [&](int bb, int kt){
    const int k0 = kt*64;
    #pragma unroll
    for (int c=0;c<4;++c)
      gload16(&P[(size_t)aRow[c]*IDIM + k0 + cb], &lds[bb + c*4096 + t*8]);
    #pragma unroll
    for (int c=0;c<2;++c)
      gload16(&WdT[ebase + (size_t)gnRow[c]*IDIM + k0 + cb], &lds[bb + 16384 + c*4096 + t*8]);
  };

  stage(0, 0);
  __syncthreads();
  int cur = 0;
  for (int kt = 0; kt < IDIM/64; ++kt){
    if (kt < IDIM/64 - 1) stage((cur^1)*24576, kt+1);
    const int bb = cur*24576;
    #pragma unroll
    for (int kk=0;kk<2;++kk){
      const int g = ((kk*4 + lq) ^ skey) * 8;
      bf16x8 a[4], b[4];
      #pragma unroll
      for (int mi=0;mi<4;++mi)
        a[mi] = *(const bf16x8*)&lds[bb + (wr*64 + mi*16 + lr)*64 + g];
      #pragma unroll
      for (int ni=0;ni<4;++ni)
        b[ni] = *(const bf16x8*)&lds[bb + 16384 + (wc*64 + ni*16 + lr)*64 + g];
      #pragma unroll
      for (int mi=0;mi<4;++mi){
        #pragma unroll
        for (int ni=0;ni<4;++ni)
          acc[mi][ni] = __builtin_amdgcn_mfma_f32_16x16x32_bf16(a[mi], b[ni], acc[mi][ni], 0,0,0);
      }
    }
    __syncthreads();
    cur ^= 1;
  }

  const int rsub = (lane>>4)*4;
  const int csub = lane & 15;
  #pragma unroll
  for (int mi=0;mi<4;++mi){
    #pragma unroll
    for (int j=0;j<4;++j){
      int gm = mt*256 + wr*64 + mi*16 + rsub + j;
      if (gm >= cnt) continue;
      size_t orow = (size_t)(off+gm)*HDIM + nt*128 + wc*64 + csub;
      #pragma unroll
      for (int ni=0;ni<4;++ni)
        part[orow + ni*16] = acc[mi][ni][j];
    }
  }
}

// ---------------- combine: out[t] = w0*part[s0] + w1*part[s1] ----------------

__global__ void combine_k(const float* __restrict__ part,
                          const int2* __restrict__ ppos,
                          const float* __restrict__ pw,
                          float* __restrict__ out){
  const int tok = blockIdx.x;
  const int c4  = threadIdx.x;
  int2 p = ppos[tok];
  float w0 = pw[p.x], w1 = pw[p.y];
  float4 a = ((const float4*)(part + (size_t)p.x*HDIM))[c4];
  float4 b = ((const float4*)(part + (size_t)p.y*HDIM))[c4];
  float4 o;
  o.x = w0*a.x + w1*b.x;
  o.y = w0*a.y + w1*b.y;
  o.z = w0*a.z + w1*b.z;
  o.w = w0*a.w + w1*b.w;
  ((float4*)(out + (size_t)tok*HDIM))[c4] = o;
}

// ---------------- launcher ----------------

extern "C" void kernel_launch(void* const* d_in, const int* in_sizes, int n_in,
                              void* d_out, int out_size, void* d_ws, size_t ws_size,
                              hipStream_t stream){
  const float* hs     = (const float*)d_in[0];
  const float* gw     = (const float*)d_in[1];
  const float* w_gate = (const float*)d_in[2];
  const float* w_up   = (const float*)d_in[3];
  const float* w_down = (const float*)d_in[4];
  float* out_final  = (float*)d_out;
  float* out_logits = out_final + (size_t)TOKENS*HDIM;

  char* wsp = (char*)d_ws;
  int*  ctl      = (int*)wsp;                       // 256 B
  int4* tokinfo  = (int4*)(wsp + 256);              // 128 KiB
  int*  ptok     = (int*)(wsp + 256 + TOKENS*16);
  float* pw      = (float*)(wsp + 256 + TOKENS*16 + NPAIRS*4);
  size_t o = 256 + (size_t)TOKENS*16 + (size_t)NPAIRS*8;
  o = (o + 255) & ~(size_t)255;
  int2* ppos = (int2*)(wsp + o);                    o += (size_t)TOKENS*8;
  unsigned short* hsb = (unsigned short*)(wsp + o); o += (size_t)TOKENS*HDIM*2;
  unsigned short* wgT = (unsigned short*)(wsp + o); o += (size_t)NEXP*IDIM*HDIM*2;
  unsigned short* wuT = (unsigned short*)(wsp + o); o += (size_t)NEXP*IDIM*HDIM*2;
  unsigned short* wdT = (unsigned short*)(wsp + o); o += (size_t)NEXP*HDIM*IDIM*2;
  unsigned short* P   = (unsigned short*)(wsp + o); o += (size_t)NPAIRS*IDIM*2;
  // part[NPAIRS][HDIM] fp32 (67.1 MB) aliases wgT+wuT (down runs after gateup)
  float* part = (float*)wgT;

  hipMemsetAsync(ctl, 0, 256, stream);

  conv_hs_k<<<(TOKENS*HDIM/4 + 255)/256, 256, 0, stream>>>((const float4*)hs, (ushort4*)hsb, TOKENS*HDIM/4);
  transpose_conv_k<<<dim3(IDIM/64, HDIM/64, NEXP), 256, 0, stream>>>(w_gate, wgT, HDIM, IDIM);
  transpose_conv_k<<<dim3(IDIM/64, HDIM/64, NEXP), 256, 0, stream>>>(w_up,   wuT, HDIM, IDIM);
  transpose_conv_k<<<dim3(HDIM/64, IDIM/64, NEXP), 256, 0, stream>>>(w_down, wdT, IDIM, HDIM);

  router_k<<<TOKENS/4, 256, 0, stream>>>(hs, gw, out_logits, tokinfo);
  hist_k  <<<TOKENS/256, 256, 0, stream>>>(tokinfo, ctl);
  scan_k  <<<1, 64, 0, stream>>>(ctl);
  assign_k<<<TOKENS/256, 256, 0, stream>>>(tokinfo, ctl, ptok, pw, ppos);

  moe_gateup_k<<<dim3(32, 16, NEXP), 512, 0, stream>>>(hsb, wgT, wuT, ptok, ctl, P);
  moe_down_k  <<<dim3(32, 8, NEXP), 512, 0, stream>>>(P, wdT, ctl, part);
  combine_k   <<<TOKENS, 256, 0, stream>>>(part, ppos, pw, out_final);
}

// Round 9
// 561.514 us; speedup vs baseline: 3.7463x; 1.0182x over previous
//
#include <hip/hip_runtime.h>
#include <hip/hip_bf16.h>

// Problem constants
#define TOKENS  8192      // B*S = 4*2048
#define HDIM    1024
#define IDIM    2048
#define NEXP    8
#define NPAIRS  16384     // TOKENS * TOP_K

typedef __attribute__((ext_vector_type(8))) short bf16x8;
typedef __attribute__((ext_vector_type(4))) float f32x4;
typedef __attribute__((ext_vector_type(8))) unsigned short u16x8;

__device__ __forceinline__ unsigned short f2b(float f){
  unsigned u = __float_as_uint(f);
  u += 0x7fff + ((u >> 16) & 1);   // round-to-nearest-even
  return (unsigned short)(u >> 16);
}

__device__ __forceinline__ void gload16(const void* g, void* l){
  __builtin_amdgcn_global_load_lds(
    (const __attribute__((address_space(1))) unsigned int*)g,
    (__attribute__((address_space(3))) unsigned int*)l, 16, 0, 0);
}

// gelu(x) = x * sigmoid(1.595769*(x + 0.044715 x^3))  (tanh-approx identity)
__device__ __forceinline__ float gelu_fast(float x){
  float z2 = 1.5957691216057308f*(x + 0.044715f*x*x*x);
  return x / (1.0f + __expf(-z2));
}

// ---------------- weight transpose+convert ----------------
// src [E][R][C] fp32 -> dst [E][C][R] bf16; 64x64 tiles, float4 loads + ushort8 stores
__global__ __launch_bounds__(256)
void transpose_conv_k(const float* __restrict__ src, unsigned short* __restrict__ dst,
                      int R, int C){
  __shared__ float tile[64][65];
  size_t base = (size_t)blockIdx.z * R * C;
  const int t = threadIdx.x;
  const int x0 = blockIdx.x*64, y0 = blockIdx.y*64;
  const int rl = t >> 4, c4 = (t & 15) * 4;
  #pragma unroll
  for (int i=0;i<4;++i){
    int r = i*16 + rl;
    float4 v = *(const float4*)&src[base + (size_t)(y0 + r)*C + x0 + c4];
    tile[r][c4+0]=v.x; tile[r][c4+1]=v.y; tile[r][c4+2]=v.z; tile[r][c4+3]=v.w;
  }
  __syncthreads();
  const int c = t >> 2, r0 = (t & 3)*16;
  size_t ob = base + (size_t)(x0 + c)*R + y0;
  #pragma unroll
  for (int v=0; v<2; ++v){
    int r = r0 + v*8;
    u16x8 o;
    #pragma unroll
    for (int j=0;j<8;++j) o[j] = f2b(tile[r+j][c]);
    *(u16x8*)&dst[ob + r] = o;
  }
}

// ---------------- routing ----------------
// ctl layout (ints): [0..7] cnt, [8..15] reserve cursor, [16..23] off

// fused: hs fp32 -> bf16 conversion + router logits + top2 (no atomics).
// one wave per token; float4 loads, ushort4 stores.
__global__ __launch_bounds__(256)
void router_conv_k(const float* __restrict__ hs, const float* __restrict__ gw,
                   float* __restrict__ lo, int4* __restrict__ tokinfo,
                   unsigned short* __restrict__ hsb){
  int wid  = (blockIdx.x*blockDim.x + threadIdx.x) >> 6;
  int lane = threadIdx.x & 63;
  const float* h = hs + (size_t)wid*HDIM;
  unsigned short* hb = hsb + (size_t)wid*HDIM;
  float a0=0,a1=0,a2=0,a3=0,a4=0,a5=0,a6=0,a7=0;
  #pragma unroll
  for (int r=0;r<4;++r){
    const int i0 = r*256 + lane*4;
    float4 v = *(const float4*)&h[i0];
    ushort4 o; o.x=f2b(v.x); o.y=f2b(v.y); o.z=f2b(v.z); o.w=f2b(v.w);
    *(ushort4*)&hb[i0] = o;
    float vv[4] = {v.x, v.y, v.z, v.w};
    #pragma unroll
    for (int j=0;j<4;++j){
      const float4 g0 = *(const float4*)(gw + (size_t)(i0+j)*NEXP);
      const float4 g1 = *(const float4*)(gw + (size_t)(i0+j)*NEXP + 4);
      a0 += vv[j]*g0.x; a1 += vv[j]*g0.y; a2 += vv[j]*g0.z; a3 += vv[j]*g0.w;
      a4 += vv[j]*g1.x; a5 += vv[j]*g1.y; a6 += vv[j]*g1.z; a7 += vv[j]*g1.w;
    }
  }
  #pragma unroll
  for (int off = 32; off; off >>= 1){
    a0 += __shfl_xor(a0, off); a1 += __shfl_xor(a1, off);
    a2 += __shfl_xor(a2, off); a3 += __shfl_xor(a3, off);
    a4 += __shfl_xor(a4, off); a5 += __shfl_xor(a5, off);
    a6 += __shfl_xor(a6, off); a7 += __shfl_xor(a7, off);
  }
  if (lane == 0){
    float v[8] = {a0,a1,a2,a3,a4,a5,a6,a7};
    float* lp = lo + (size_t)wid*NEXP;
    #pragma unroll
    for (int e=0;e<8;++e) lp[e] = v[e];
    int e0 = 0; float b0 = v[0];
    #pragma unroll
    for (int e=1;e<8;++e){ if (v[e] > b0){ b0 = v[e]; e0 = e; } }
    int e1 = 0; float b1 = -1e30f;
    #pragma unroll
    for (int e=0;e<8;++e){ if (e != e0 && v[e] > b1){ b1 = v[e]; e1 = e; } }
    float ex = expf(b1 - b0);
    float w0 = 1.0f/(1.0f+ex);
    float w1 = ex/(1.0f+ex);
    tokinfo[wid] = make_int4(e0, e1, __float_as_int(w0), __float_as_int(w1));
  }
}

// per-block LDS histogram -> 8 global atomics per block
__global__ __launch_bounds__(256)
void hist_k(const int4* __restrict__ tokinfo, int* __restrict__ ctl){
  __shared__ int h[8];
  if (threadIdx.x < 8) h[threadIdx.x] = 0;
  __syncthreads();
  int4 ti = tokinfo[blockIdx.x*256 + threadIdx.x];
  atomicAdd(&h[ti.x], 1); atomicAdd(&h[ti.y], 1);
  __syncthreads();
  if (threadIdx.x < 8) atomicAdd(&ctl[threadIdx.x], h[threadIdx.x]);
}

__global__ void scan_k(int* ctl){
  if (threadIdx.x == 0){
    int s = 0;
    #pragma unroll
    for (int e=0;e<NEXP;++e){ ctl[16+e] = s; s += ctl[e]; }
  }
}

// atomic-light assign: ballot/popc ranks + one atomicAdd per (block,expert)
__global__ __launch_bounds__(256)
void assign_k(const int4* __restrict__ tokinfo, int* ctl,
              int* __restrict__ ptok, float* __restrict__ pw,
              int2* __restrict__ ppos){
  __shared__ int wcnt0[4][8], wcnt1[4][8];
  __shared__ int woff0[4][8], woff1[4][8];
  __shared__ int btot0[8], blkbase[8];
  const int tid = threadIdx.x, lane = tid & 63, wv = tid >> 6;
  const int tok = blockIdx.x*256 + tid;
  int4 ti = tokinfo[tok];
  const unsigned long long below = (1ull << lane) - 1ull;
  int r0 = 0, r1 = 0;
  #pragma unroll
  for (int e=0;e<8;++e){
    unsigned long long b0 = __ballot(ti.x == e);
    unsigned long long b1 = __ballot(ti.y == e);
    if (ti.x == e) r0 = __popcll(b0 & below);
    if (ti.y == e) r1 = __popcll(b1 & below);
    if (lane == 0){ wcnt0[wv][e] = __popcll(b0); wcnt1[wv][e] = __popcll(b1); }
  }
  __syncthreads();
  if (tid < 8){
    const int e = tid;
    int s0 = 0, s1 = 0;
    #pragma unroll
    for (int w=0;w<4;++w){ woff0[w][e] = s0; s0 += wcnt0[w][e]; }
    btot0[e] = s0;
    #pragma unroll
    for (int w=0;w<4;++w){ woff1[w][e] = s1; s1 += wcnt1[w][e]; }
    blkbase[e] = atomicAdd(&ctl[8+e], s0 + s1);
  }
  __syncthreads();
  const int e0 = ti.x, e1 = ti.y;
  int p0 = ctl[16+e0] + blkbase[e0] + woff0[wv][e0] + r0;
  int p1 = ctl[16+e1] + blkbase[e1] + btot0[e1] + woff1[wv][e1] + r1;
  ptok[p0] = tok; pw[p0] = __int_as_float(ti.z);
  ptok[p1] = tok; pw[p1] = __int_as_float(ti.w);
  ppos[tok] = make_int2(p0, p1);
}

// ---------------- fused gate+up GEMM ----------------
// 128x128 tile, 256 thr (4 waves of 64x64), BK=32, dbuf 48KB -> 2 blocks/CU.
// Independent blocks decouple barrier stalls (m114 cross-block overlap).
// T2 swizzle both-sides, 2-bit key (4 granules per 64B row).

__global__ __launch_bounds__(256, 2)
void moe_gateup_k(const unsigned short* __restrict__ X,
                  const unsigned short* __restrict__ WgT,
                  const unsigned short* __restrict__ WuT,
                  const int* __restrict__ ptok,
                  const int* __restrict__ ctl,
                  unsigned short* __restrict__ P){
  __shared__ unsigned short lds[2*12288];   // 48 KiB: per buf A[128*32] G[128*32] U[128*32]
  const int e  = blockIdx.z;
  const int wg = blockIdx.x + 64*blockIdx.y;      // 0..1023
  const int id = (wg & 7)*128 + (wg >> 3);        // XCD-chunked, bijective
  const int mt = id & 63;
  const int nt = id >> 6;                         // 0..15
  const int cnt = ctl[e];
  if (mt*128 >= cnt) return;
  const int off = ctl[16+e];
  const int t = threadIdx.x;
  const int lane = t & 63, w = t >> 6;            // 4 waves
  const int wr = w >> 1, wc = w & 1;              // 2x2 of 64x64

  const int r_in = t >> 2;                        // 0..63 rows/round
  const int cb   = (((t & 3) ^ (r_in & 3)) * 8);  // inverse-swizzled src granule

  int tokRow[2];
  #pragma unroll
  for (int c=0;c<2;++c){
    int gm = mt*128 + c*64 + r_in;
    tokRow[c] = ptok[off + (gm < cnt ? gm : 0)];
  }
  const size_t ebase = (size_t)e * IDIM * HDIM;
  int gnRow[2];
  #pragma unroll
  for (int c=0;c<2;++c) gnRow[c] = nt*128 + c*64 + r_in;

  f32x4 accG[4][4] = {};
  f32x4 accU[4][4] = {};

  const int lq = lane >> 4, lr = lane & 15;

  auto stage = [&](int bb, int kt){
    const int k0 = kt*32;
    #pragma unroll
    for (int c=0;c<2;++c)
      gload16(&X[(size_t)tokRow[c]*HDIM + k0 + cb], &lds[bb + c*2048 + t*8]);
    #pragma unroll
    for (int c=0;c<2;++c){
      gload16(&WgT[ebase + (size_t)gnRow[c]*HDIM + k0 + cb], &lds[bb + 4096 + c*2048 + t*8]);
      gload16(&WuT[ebase + (size_t)gnRow[c]*HDIM + k0 + cb], &lds[bb + 8192 + c*2048 + t*8]);
    }
  };

  stage(0, 0);
  __syncthreads();
  int cur = 0;
  for (int kt = 0; kt < HDIM/32; ++kt){
    if (kt < HDIM/32 - 1) stage((cur^1)*12288, kt+1);
    const int bb = cur*12288;
    const int g = ((lq ^ (lr & 3)) * 8);
    bf16x8 a[4], bg[4], bu[4];
    #pragma unroll
    for (int mi=0;mi<4;++mi)
      a[mi] = *(const bf16x8*)&lds[bb + (wr*64 + mi*16 + lr)*32 + g];
    #pragma unroll
    for (int ni=0;ni<4;++ni){
      bg[ni] = *(const bf16x8*)&lds[bb + 4096 + (wc*64 + ni*16 + lr)*32 + g];
      bu[ni] = *(const bf16x8*)&lds[bb + 8192 + (wc*64 + ni*16 + lr)*32 + g];
    }
    #pragma unroll
    for (int mi=0;mi<4;++mi){
      #pragma unroll
      for (int ni=0;ni<4;++ni){
        accG[mi][ni] = __builtin_amdgcn_mfma_f32_16x16x32_bf16(a[mi], bg[ni], accG[mi][ni], 0,0,0);
        accU[mi][ni] = __builtin_amdgcn_mfma_f32_16x16x32_bf16(a[mi], bu[ni], accU[mi][ni], 0,0,0);
      }
    }
    __syncthreads();
    cur ^= 1;
  }

  // epilogue (C/D: col=lane&15, row=(lane>>4)*4+reg)
  const int rsub = (lane>>4)*4;
  const int csub = lane & 15;
  #pragma unroll
  for (int mi=0;mi<4;++mi){
    #pragma unroll
    for (int j=0;j<4;++j){
      int gm = mt*128 + wr*64 + mi*16 + rsub + j;
      if (gm >= cnt) continue;
      size_t prow = (size_t)(off+gm)*IDIM + nt*128 + wc*64 + csub;
      #pragma unroll
      for (int ni=0;ni<4;++ni){
        float g2 = accG[mi][ni][j];
        float u  = accU[mi][ni][j];
        P[prow + ni*16] = f2b(gelu_fast(g2)*u);
      }
    }
  }
}

// ---------------- down GEMM ----------------
// 128x128 tile, 256 thr (4 waves of 64x64), BK=64, dbuf 64KB -> 2 blocks/CU.

__global__ __launch_bounds__(256, 2)
void moe_down_k(const unsigned short* __restrict__ P,
                const unsigned short* __restrict__ WdT,
                const int* __restrict__ ctl,
                float* __restrict__ part){
  __shared__ unsigned short lds[2*16384];   // 64 KiB: per buf A[128*64] B[128*64]
  const int e  = blockIdx.z;
  const int wg = blockIdx.x + 64*blockIdx.y;      // 0..511
  const int id = (wg & 7)*64 + (wg >> 3);
  const int mt = id & 63;
  const int nt = id >> 6;                         // 0..7
  const int cnt = ctl[e];
  if (mt*128 >= cnt) return;
  const int off = ctl[16+e];
  const int t = threadIdx.x;
  const int lane = t & 63, w = t >> 6;
  const int wr = w >> 1, wc = w & 1;

  const int r_in = t >> 3;                        // 0..31 rows/round
  const int cb   = (((t & 7) ^ (r_in & 7)) * 8);

  int aRow[4];
  #pragma unroll
  for (int c=0;c<4;++c){
    int gm = mt*128 + c*32 + r_in;
    aRow[c] = off + (gm < cnt ? gm : cnt-1);
  }
  const size_t ebase = (size_t)e * HDIM * IDIM;
  int gnRow[4];
  #pragma unroll
  for (int c=0;c<4;++c) gnRow[c] = nt*128 + c*32 + r_in;

  f32x4 acc[4][4] = {};

  const int lq = lane >> 4, lr = lane & 15;

  auto stage = [&](int bb, int kt){
    const int k0 = kt*64;
    #pragma unroll
    for (int c=0;c<4;++c)
      gload16(&P[(size_t)aRow[c]*IDIM + k0 + cb], &lds[bb + c*2048 + t*8]);
    #pragma unroll
    for (int c=0;c<4;++c)
      gload16(&WdT[ebase + (size_t)gnRow[c]*IDIM + k0 + cb], &lds[bb + 8192 + c*2048 + t*8]);
  };

  stage(0, 0);
  __syncthreads();
  int cur = 0;
  for (int kt = 0; kt < IDIM/64; ++kt){
    if (kt < IDIM/64 - 1) stage((cur^1)*16384, kt+1);
    const int bb = cur*16384;
    #pragma unroll
    for (int kk=0;kk<2;++kk){
      const int g = ((kk*4 + lq) ^ (lr & 7)) * 8;
      bf16x8 a[4], b[4];
      #pragma unroll
      for (int mi=0;mi<4;++mi)
        a[mi] = *(const bf16x8*)&lds[bb + (wr*64 + mi*16 + lr)*64 + g];
      #pragma unroll
      for (int ni=0;ni<4;++ni)
        b[ni] = *(const bf16x8*)&lds[bb + 8192 + (wc*64 + ni*16 + lr)*64 + g];
      #pragma unroll
      for (int mi=0;mi<4;++mi){
        #pragma unroll
        for (int ni=0;ni<4;++ni)
          acc[mi][ni] = __builtin_amdgcn_mfma_f32_16x16x32_bf16(a[mi], b[ni], acc[mi][ni], 0,0,0);
      }
    }
    __syncthreads();
    cur ^= 1;
  }

  const int rsub = (lane>>4)*4;
  const int csub = lane & 15;
  #pragma unroll
  for (int mi=0;mi<4;++mi){
    #pragma unroll
    for (int j=0;j<4;++j){
      int gm = mt*128 + wr*64 + mi*16 + rsub + j;
      if (gm >= cnt) continue;
      size_t orow = (size_t)(off+gm)*HDIM + nt*128 + wc*64 + csub;
      #pragma unroll
      for (int ni=0;ni<4;++ni)
        part[orow + ni*16] = acc[mi][ni][j];
    }
  }
}

// ---------------- combine: out[t] = w0*part[s0] + w1*part[s1] ----------------

__global__ void combine_k(const float* __restrict__ part,
                          const int2* __restrict__ ppos,
                          const float* __restrict__ pw,
                          float* __restrict__ out){
  const int tok = blockIdx.x;
  const int c4  = threadIdx.x;
  int2 p = ppos[tok];
  float w0 = pw[p.x], w1 = pw[p.y];
  float4 a = ((const float4*)(part + (size_t)p.x*HDIM))[c4];
  float4 b = ((const float4*)(part + (size_t)p.y*HDIM))[c4];
  float4 o;
  o.x = w0*a.x + w1*b.x;
  o.y = w0*a.y + w1*b.y;
  o.z = w0*a.z + w1*b.z;
  o.w = w0*a.w + w1*b.w;
  ((float4*)(out + (size_t)tok*HDIM))[c4] = o;
}

// ---------------- launcher ----------------

extern "C" void kernel_launch(void* const* d_in, const int* in_sizes, int n_in,
                              void* d_out, int out_size, void* d_ws, size_t ws_size,
                              hipStream_t stream){
  const float* hs     = (const float*)d_in[0];
  const float* gw     = (const float*)d_in[1];
  const float* w_gate = (const float*)d_in[2];
  const float* w_up   = (const float*)d_in[3];
  const float* w_down = (const float*)d_in[4];
  float* out_final  = (float*)d_out;
  float* out_logits = out_final + (size_t)TOKENS*HDIM;

  char* wsp = (char*)d_ws;
  int*  ctl      = (int*)wsp;                       // 256 B
  int4* tokinfo  = (int4*)(wsp + 256);              // 128 KiB
  int*  ptok     = (int*)(wsp + 256 + TOKENS*16);
  float* pw      = (float*)(wsp + 256 + TOKENS*16 + NPAIRS*4);
  size_t o = 256 + (size_t)TOKENS*16 + (size_t)NPAIRS*8;
  o = (o + 255) & ~(size_t)255;
  int2* ppos = (int2*)(wsp + o);                    o += (size_t)TOKENS*8;
  unsigned short* hsb = (unsigned short*)(wsp + o); o += (size_t)TOKENS*HDIM*2;
  unsigned short* wgT = (unsigned short*)(wsp + o); o += (size_t)NEXP*IDIM*HDIM*2;
  unsigned short* wuT = (unsigned short*)(wsp + o); o += (size_t)NEXP*IDIM*HDIM*2;
  unsigned short* wdT = (unsigned short*)(wsp + o); o += (size_t)NEXP*HDIM*IDIM*2;
  unsigned short* P   = (unsigned short*)(wsp + o); o += (size_t)NPAIRS*IDIM*2;
  // part[NPAIRS][HDIM] fp32 (67.1 MB) aliases wgT+wuT (down runs after gateup)
  float* part = (float*)wgT;

  hipMemsetAsync(ctl, 0, 256, stream);

  transpose_conv_k<<<dim3(IDIM/64, HDIM/64, NEXP), 256, 0, stream>>>(w_gate, wgT, HDIM, IDIM);
  transpose_conv_k<<<dim3(IDIM/64, HDIM/64, NEXP), 256, 0, stream>>>(w_up,   wuT, HDIM, IDIM);
  transpose_conv_k<<<dim3(HDIM/64, IDIM/64, NEXP), 256, 0, stream>>>(w_down, wdT, IDIM, HDIM);

  router_conv_k<<<TOKENS/4, 256, 0, stream>>>(hs, gw, out_logits, tokinfo, hsb);
  hist_k  <<<TOKENS/256, 256, 0, stream>>>(tokinfo, ctl);
  scan_k  <<<1, 64, 0, stream>>>(ctl);
  assign_k<<<TOKENS/256, 256, 0, stream>>>(tokinfo, ctl, ptok, pw, ppos);

  moe_gateup_k<<<dim3(64, 16, NEXP), 256, 0, stream>>>(hsb, wgT, wuT, ptok, ctl, P);
  moe_down_k  <<<dim3(64, 8, NEXP), 256, 0, stream>>>(P, wdT, ctl, part);
  combine_k   <<<TOKENS, 256, 0, stream>>>(part, ppos, pw, out_final);
}